// Round 1
// baseline (1545.172 us; speedup 1.0000x reference)
//
#include <hip/hip_runtime.h>

typedef __attribute__((ext_vector_type(4))) float f32x4;
typedef __attribute__((ext_vector_type(8))) short bf16x8;
typedef __attribute__((ext_vector_type(4))) unsigned short u16x4;

__device__ __forceinline__ unsigned short f2bf(float f) {
  unsigned int u = __builtin_bit_cast(unsigned int, f);
  u += 0x7fffu + ((u >> 16) & 1u);   // round-to-nearest-even
  return (unsigned short)(u >> 16);
}
__device__ __forceinline__ float bf2f(unsigned short h) {
  unsigned int u = ((unsigned int)h) << 16;
  return __builtin_bit_cast(float, u);
}

// ---------------- prep kernels ----------------
__global__ void fill_deg_k(float* __restrict__ deg, int n) {
  int i = blockIdx.x * blockDim.x + threadIdx.x;
  if (i < n) deg[i] = 1.0f;  // self-loop weight
}
__global__ void edge_deg_k(const int* __restrict__ dst, const float* __restrict__ ew,
                           float* __restrict__ deg, int E) {
  int e = blockIdx.x * blockDim.x + threadIdx.x;
  if (e < E) atomicAdd(&deg[dst[e]], ew[e]);
}
__global__ void rsqrt_inplace_k(float* __restrict__ deg, int n) {
  int i = blockIdx.x * blockDim.x + threadIdx.x;
  if (i < n) deg[i] = rsqrtf(deg[i]);  // deg >= 1 always (self-loops)
}
__global__ void norm_k(const int* __restrict__ src, const int* __restrict__ dst,
                       const float* __restrict__ ew, const float* __restrict__ dinv,
                       float* __restrict__ nrm, int E) {
  int e = blockIdx.x * blockDim.x + threadIdx.x;
  if (e < E) nrm[e] = dinv[src[e]] * ew[e] * dinv[dst[e]];
}
// W [K][N] fp32 -> Wt [N][K] bf16
__global__ void conv_wt_k(const float* __restrict__ W, unsigned short* __restrict__ Wt,
                          int K, int N) {
  int idx = blockIdx.x * blockDim.x + threadIdx.x;
  if (idx < K * N) {
    int n = idx / K, k = idx - n * K;
    Wt[idx] = f2bf(W[(size_t)k * N + n]);
  }
}

// ---------------- bf16 MFMA GEMM ----------------
// A [M][KD] fp32 (optional relu on load), Wt [NC][KD] bf16 (pre-transposed).
// Writes Hb [M][NC] bf16 and Oinit [M][NC] = bias[c] + h*dinv[r]^2 (self-loop + bias).
template<int NC, int KD, bool RELU>
__launch_bounds__(256, 2)
__global__ void gemm_k(const float* __restrict__ A, const unsigned short* __restrict__ Wt,
                       const float* __restrict__ bias, const float* __restrict__ dinv,
                       unsigned short* __restrict__ Hb, float* __restrict__ Oinit, int M) {
  constexpr int BM = 128, BK = 64;
  constexpr int WN = 64;
  constexpr int WGN = NC / WN;             // waves along N: 2 (NC=128) or 1 (NC=64)
  constexpr int WGM = 4 / WGN;             // waves along M: 2 or 4
  constexpr int WM = BM / WGM;             // 64 or 32
  constexpr int FM = WM / 16;              // 4 or 2
  constexpr int FN = WN / 16;              // 4
  constexpr int KSUB = BK / 32;            // 2
  constexpr int A_PER_T = BM * (BK / 4) / 256;  // float4 chunks per thread = 8
  constexpr int B_PER_T = NC * (BK / 8) / 256;  // 16B chunks per thread = 4 or 2
  constexpr int nT = KD / BK;

  __shared__ unsigned short As[BM * BK];
  __shared__ unsigned short Bs[NC * BK];
  char* asb = reinterpret_cast<char*>(As);
  char* bsb = reinterpret_cast<char*>(Bs);

  const int tid = threadIdx.x;
  const int lane = tid & 63;
  const int wid = tid >> 6;
  const int wr = wid / WGN;
  const int wc = wid % WGN;
  const int lg = lane >> 4;   // k-group 0..3
  const int lr = lane & 15;   // row/col within fragment
  const int blockM = blockIdx.x * BM;

  float4 areg[A_PER_T];
  uint4 breg[B_PER_T];

  auto load_tiles = [&](int k0) {
#pragma unroll
    for (int i = 0; i < A_PER_T; ++i) {
      int chunk = tid + i * 256;
      int r = chunk >> 4, c4 = chunk & 15;
      int gr = blockM + r; if (gr >= M) gr = M - 1;  // clamp; not stored later
      areg[i] = *reinterpret_cast<const float4*>(A + (size_t)gr * KD + k0 + c4 * 4);
    }
#pragma unroll
    for (int i = 0; i < B_PER_T; ++i) {
      int chunk = tid + i * 256;
      int n = chunk >> 3, c = chunk & 7;
      breg[i] = *reinterpret_cast<const uint4*>(Wt + (size_t)n * KD + k0 + c * 8);
    }
  };

  f32x4 acc[FM][FN] = {};

  load_tiles(0);

  for (int t = 0; t < nT; ++t) {
    __syncthreads();  // prev iter's LDS reads done
#pragma unroll
    for (int i = 0; i < A_PER_T; ++i) {
      int chunk = tid + i * 256;
      int r = chunk >> 4, c4 = chunk & 15;
      float4 v = areg[i];
      if (RELU) {
        v.x = fmaxf(v.x, 0.f); v.y = fmaxf(v.y, 0.f);
        v.z = fmaxf(v.z, 0.f); v.w = fmaxf(v.w, 0.f);
      }
      u16x4 p = { f2bf(v.x), f2bf(v.y), f2bf(v.z), f2bf(v.w) };
      int byte = r * (BK * 2) + ((c4 * 8) ^ ((r & 7) << 4));  // XOR swizzle (T2)
      *reinterpret_cast<u16x4*>(asb + byte) = p;
    }
#pragma unroll
    for (int i = 0; i < B_PER_T; ++i) {
      int chunk = tid + i * 256;
      int n = chunk >> 3, c = chunk & 7;
      int byte = n * (BK * 2) + ((c * 16) ^ ((n & 7) << 4));
      *reinterpret_cast<uint4*>(bsb + byte) = breg[i];
    }
    __syncthreads();  // LDS ready
    if (t + 1 < nT) load_tiles((t + 1) * BK);  // overlap next loads with MFMA

    bf16x8 af[FM][KSUB], bfr[FN][KSUB];
#pragma unroll
    for (int fm = 0; fm < FM; ++fm)
#pragma unroll
      for (int kk = 0; kk < KSUB; ++kk) {
        int row = wr * WM + fm * 16 + lr;
        int k = kk * 32 + lg * 8;
        int byte = row * (BK * 2) + ((k * 2) ^ ((row & 7) << 4));
        af[fm][kk] = *reinterpret_cast<const bf16x8*>(asb + byte);
      }
#pragma unroll
    for (int fn = 0; fn < FN; ++fn)
#pragma unroll
      for (int kk = 0; kk < KSUB; ++kk) {
        int n = wc * WN + fn * 16 + lr;
        int k = kk * 32 + lg * 8;
        int byte = n * (BK * 2) + ((k * 2) ^ ((n & 7) << 4));
        bfr[fn][kk] = *reinterpret_cast<const bf16x8*>(bsb + byte);
      }
#pragma unroll
    for (int kk = 0; kk < KSUB; ++kk)
#pragma unroll
      for (int fm = 0; fm < FM; ++fm)
#pragma unroll
        for (int fn = 0; fn < FN; ++fn)
          acc[fm][fn] = __builtin_amdgcn_mfma_f32_16x16x32_bf16(
              af[fm][kk], bfr[fn][kk], acc[fm][fn], 0, 0, 0);
  }

  // epilogue: C/D layout col = lane&15, row = (lane>>4)*4 + j
#pragma unroll
  for (int fm = 0; fm < FM; ++fm) {
#pragma unroll
    for (int fn = 0; fn < FN; ++fn) {
      int col = wc * WN + fn * 16 + lr;
      float bcol = bias[col];
#pragma unroll
      for (int j = 0; j < 4; ++j) {
        int row = blockM + wr * WM + fm * 16 + lg * 4 + j;
        if (row < M) {
          float h = acc[fm][fn][j];
          float di = dinv[row];
          Hb[(size_t)row * NC + col] = f2bf(h);
          Oinit[(size_t)row * NC + col] = bcol + h * di * di;
        }
      }
    }
  }
}

// ---------------- edge aggregation (COO, wave per edge) ----------------
template<int D>
__global__ void agg_edges_k(const int* __restrict__ src, const int* __restrict__ dst,
                            const float* __restrict__ nrm, const unsigned short* __restrict__ h,
                            float* __restrict__ out, int E) {
  const int lane = threadIdx.x & 63;
  const int wid = (blockIdx.x * blockDim.x + threadIdx.x) >> 6;
  const int nw = (gridDim.x * blockDim.x) >> 6;
  for (int e = wid; e < E; e += nw) {
    int s = __builtin_amdgcn_readfirstlane(src[e]);
    int d = __builtin_amdgcn_readfirstlane(dst[e]);
    float nm = nrm[e];
    if (D == 128) {
      float v0 = bf2f(h[(size_t)s * 128 + lane]) * nm;
      float v1 = bf2f(h[(size_t)s * 128 + 64 + lane]) * nm;
      atomicAdd(&out[(size_t)d * 128 + lane], v0);
      atomicAdd(&out[(size_t)d * 128 + 64 + lane], v1);
    } else {
      float v0 = bf2f(h[(size_t)s * D + lane]) * nm;
      atomicAdd(&out[(size_t)d * D + lane], v0);
    }
  }
}

__global__ void agg_scalar_k(const int* __restrict__ src, const int* __restrict__ dst,
                             const float* __restrict__ nrm, const float* __restrict__ h3,
                             float* __restrict__ out, int E) {
  int e = blockIdx.x * blockDim.x + threadIdx.x;
  if (e < E) atomicAdd(&out[dst[e]], h3[src[e]] * nrm[e]);
}

// ---------------- layer-3 GEMV (D=64 -> 1) ----------------
__global__ void gemv3_k(const float* __restrict__ o2, const float* __restrict__ W3,
                        const float* __restrict__ b3, const float* __restrict__ dinv,
                        float* __restrict__ h3, float* __restrict__ out, int M) {
  int lane = threadIdx.x & 63;
  int row = blockIdx.x * (blockDim.x >> 6) + (threadIdx.x >> 6);
  if (row >= M) return;
  float v = fmaxf(o2[(size_t)row * 64 + lane], 0.f) * W3[lane];
#pragma unroll
  for (int off = 32; off > 0; off >>= 1) v += __shfl_xor(v, off, 64);
  if (lane == 0) {
    float di = dinv[row];
    h3[row] = v;
    out[row] = b3[0] + v * di * di;
  }
}

// ---------------- launch ----------------
extern "C" void kernel_launch(void* const* d_in, const int* in_sizes, int n_in,
                              void* d_out, int out_size, void* d_ws, size_t ws_size,
                              hipStream_t stream) {
  const float* x  = (const float*)d_in[0];
  const int*   ei = (const int*)d_in[1];
  const float* ea = (const float*)d_in[2];
  const float* W1 = (const float*)d_in[3];
  const float* b1 = (const float*)d_in[4];
  const float* W2 = (const float*)d_in[5];
  const float* b2 = (const float*)d_in[6];
  const float* W3 = (const float*)d_in[7];
  const float* b3 = (const float*)d_in[8];
  float* out = (float*)d_out;

  const int N = in_sizes[0] / 512;  // 100000
  const int E = in_sizes[2];        // 1600000
  const int* src = ei;
  const int* dst = ei + E;

  char* w = (char*)d_ws;
  auto alloc = [&](size_t bytes) {
    char* p = w; w += (bytes + 511) & ~(size_t)511; return p;
  };
  float* dinv          = (float*)alloc((size_t)N * 4);          // deg -> dinv in place
  float* nrm           = (float*)alloc((size_t)E * 4);
  unsigned short* h1   = (unsigned short*)alloc((size_t)N * 128 * 2);
  float* o1            = (float*)alloc((size_t)N * 128 * 4);
  unsigned short* h2   = (unsigned short*)alloc((size_t)N * 64 * 2);
  float* o2            = (float*)alloc((size_t)N * 64 * 4);
  float* h3            = (float*)alloc((size_t)N * 4);
  unsigned short* wt1  = (unsigned short*)alloc(512 * 128 * 2);
  unsigned short* wt2  = (unsigned short*)alloc(128 * 64 * 2);

  const int TB = 256;
  // prep: deg, dinv, norm (shared by all 3 layers), weight transpose+bf16
  fill_deg_k<<<(N + TB - 1) / TB, TB, 0, stream>>>(dinv, N);
  edge_deg_k<<<(E + TB - 1) / TB, TB, 0, stream>>>(dst, ea, dinv, E);
  rsqrt_inplace_k<<<(N + TB - 1) / TB, TB, 0, stream>>>(dinv, N);
  norm_k<<<(E + TB - 1) / TB, TB, 0, stream>>>(src, dst, ea, dinv, nrm, E);
  conv_wt_k<<<(512 * 128 + TB - 1) / TB, TB, 0, stream>>>(W1, wt1, 512, 128);
  conv_wt_k<<<(128 * 64 + TB - 1) / TB, TB, 0, stream>>>(W2, wt2, 128, 64);

  const int gblocks = (N + 127) / 128;
  // layer 1
  gemm_k<128, 512, false><<<gblocks, TB, 0, stream>>>(x, wt1, b1, dinv, h1, o1, N);
  agg_edges_k<128><<<2048, TB, 0, stream>>>(src, dst, nrm, h1, o1, E);
  // layer 2 (relu fused into A-load)
  gemm_k<64, 128, true><<<gblocks, TB, 0, stream>>>(o1, wt2, b2, dinv, h2, o2, N);
  agg_edges_k<64><<<2048, TB, 0, stream>>>(src, dst, nrm, h2, o2, E);
  // layer 3 (relu fused into GEMV)
  gemv3_k<<<(N + 3) / 4, TB, 0, stream>>>(o2, W3, b3, dinv, h3, out, N);
  agg_scalar_k<<<(E + TB - 1) / TB, TB, 0, stream>>>(src, dst, nrm, h3, out, E);
}

// Round 2
// 806.403 us; speedup vs baseline: 1.9161x; 1.9161x over previous
//
#include <hip/hip_runtime.h>

typedef __attribute__((ext_vector_type(4))) float f32x4;
typedef __attribute__((ext_vector_type(8))) short bf16x8;
typedef __attribute__((ext_vector_type(4))) unsigned short u16x4;

__device__ __forceinline__ unsigned short f2bf(float f) {
  unsigned int u = __builtin_bit_cast(unsigned int, f);
  u += 0x7fffu + ((u >> 16) & 1u);   // round-to-nearest-even
  return (unsigned short)(u >> 16);
}
__device__ __forceinline__ float bf2f(unsigned short h) {
  unsigned int u = ((unsigned int)h) << 16;
  return __builtin_bit_cast(float, u);
}
__device__ __forceinline__ float bflo(unsigned int u) { return bf2f((unsigned short)(u & 0xffffu)); }
__device__ __forceinline__ float bfhi(unsigned int u) { return bf2f((unsigned short)(u >> 16)); }

// ---------------- prep kernels ----------------
__global__ void fill_deg_k(float* __restrict__ deg, int n) {
  int i = blockIdx.x * blockDim.x + threadIdx.x;
  if (i < n) deg[i] = 1.0f;  // self-loop weight
}
// fused: weighted in-degree + edge count per dst
__global__ void edge_prep_k(const int* __restrict__ dst, const float* __restrict__ ew,
                            float* __restrict__ deg, int* __restrict__ cnt, int E) {
  int e = blockIdx.x * blockDim.x + threadIdx.x;
  if (e < E) {
    int d = dst[e];
    atomicAdd(&deg[d], ew[e]);
    atomicAdd(&cnt[d], 1);
  }
}
__global__ void rsqrt_inplace_k(float* __restrict__ deg, int n) {
  int i = blockIdx.x * blockDim.x + threadIdx.x;
  if (i < n) deg[i] = rsqrtf(deg[i]);  // deg >= 1 always (self-loops)
}
// W [K][N] fp32 -> Wt [N][K] bf16
__global__ void conv_wt_k(const float* __restrict__ W, unsigned short* __restrict__ Wt,
                          int K, int N) {
  int idx = blockIdx.x * blockDim.x + threadIdx.x;
  if (idx < K * N) {
    int n = idx / K, k = idx - n * K;
    Wt[idx] = f2bf(W[(size_t)k * N + n]);
  }
}

// ---------------- CSR build: exclusive scan (3 kernels) + scatter ----------------
__global__ void scan1_k(const int* __restrict__ cnt, int* __restrict__ row,
                        int* __restrict__ bsum, int N) {
  __shared__ int sh[256];
  const int tid = threadIdx.x;
  const int base = blockIdx.x * 2048 + tid * 8;
  int v[8]; int s = 0;
#pragma unroll
  for (int i = 0; i < 8; ++i) {
    int idx = base + i;
    v[i] = (idx < N) ? cnt[idx] : 0;
    s += v[i];
  }
  sh[tid] = s;
  __syncthreads();
  for (int off = 1; off < 256; off <<= 1) {
    int t = (tid >= off) ? sh[tid - off] : 0;
    __syncthreads();
    sh[tid] += t;
    __syncthreads();
  }
  int excl = sh[tid] - s;
  if (tid == 255) bsum[blockIdx.x] = sh[255];
  int run = excl;
#pragma unroll
  for (int i = 0; i < 8; ++i) {
    int idx = base + i;
    if (idx < N) row[idx] = run;
    run += v[i];
  }
}
__global__ void scan2_k(int* __restrict__ bsum, int nb) {
  if (threadIdx.x == 0 && blockIdx.x == 0) {
    int run = 0;
    for (int i = 0; i < nb; ++i) { int t = bsum[i]; bsum[i] = run; run += t; }
  }
}
__global__ void scan3_k(int* __restrict__ row, const int* __restrict__ bsum, int N, int E) {
  int idx = blockIdx.x * blockDim.x + threadIdx.x;
  if (idx < N) row[idx] += bsum[idx >> 11];
  if (idx == N) row[N] = E;
}
// pack (src, dinv[src]*ew*dinv[dst]) sorted by dst
__global__ void scatter_k(const int* __restrict__ src, const int* __restrict__ dst,
                          const float* __restrict__ ew, const float* __restrict__ dinv,
                          const int* __restrict__ row, int* __restrict__ cur,
                          uint2* __restrict__ eadj, int E) {
  int e = blockIdx.x * blockDim.x + threadIdx.x;
  if (e >= E) return;
  int s = src[e], d = dst[e];
  float nm = dinv[s] * ew[e] * dinv[d];
  int pos = row[d] + atomicAdd(&cur[d], 1);
  eadj[pos] = make_uint2((unsigned)s, __builtin_bit_cast(unsigned, nm));
}

// ---------------- bf16 MFMA GEMM (writes Hb bf16 only) ----------------
template<int NC, int KD, bool RELU>
__launch_bounds__(256, 2)
__global__ void gemm_k(const float* __restrict__ A, const unsigned short* __restrict__ Wt,
                       unsigned short* __restrict__ Hb, int M) {
  constexpr int BM = 128, BK = 64;
  constexpr int WN = 64;
  constexpr int WGN = NC / WN;
  constexpr int WGM = 4 / WGN;
  constexpr int WM = BM / WGM;
  constexpr int FM = WM / 16;
  constexpr int FN = WN / 16;
  constexpr int KSUB = BK / 32;
  constexpr int A_PER_T = BM * (BK / 4) / 256;
  constexpr int B_PER_T = NC * (BK / 8) / 256;
  constexpr int nT = KD / BK;

  __shared__ unsigned short As[BM * BK];
  __shared__ unsigned short Bs[NC * BK];
  char* asb = reinterpret_cast<char*>(As);
  char* bsb = reinterpret_cast<char*>(Bs);

  const int tid = threadIdx.x;
  const int lane = tid & 63;
  const int wid = tid >> 6;
  const int wr = wid / WGN;
  const int wc = wid % WGN;
  const int lg = lane >> 4;
  const int lr = lane & 15;
  const int blockM = blockIdx.x * BM;

  float4 areg[A_PER_T];
  uint4 breg[B_PER_T];

  auto load_tiles = [&](int k0) {
#pragma unroll
    for (int i = 0; i < A_PER_T; ++i) {
      int chunk = tid + i * 256;
      int r = chunk >> 4, c4 = chunk & 15;
      int gr = blockM + r; if (gr >= M) gr = M - 1;
      areg[i] = *reinterpret_cast<const float4*>(A + (size_t)gr * KD + k0 + c4 * 4);
    }
#pragma unroll
    for (int i = 0; i < B_PER_T; ++i) {
      int chunk = tid + i * 256;
      int n = chunk >> 3, c = chunk & 7;
      breg[i] = *reinterpret_cast<const uint4*>(Wt + (size_t)n * KD + k0 + c * 8);
    }
  };

  f32x4 acc[FM][FN] = {};
  load_tiles(0);

  for (int t = 0; t < nT; ++t) {
    __syncthreads();
#pragma unroll
    for (int i = 0; i < A_PER_T; ++i) {
      int chunk = tid + i * 256;
      int r = chunk >> 4, c4 = chunk & 15;
      float4 v = areg[i];
      if (RELU) {
        v.x = fmaxf(v.x, 0.f); v.y = fmaxf(v.y, 0.f);
        v.z = fmaxf(v.z, 0.f); v.w = fmaxf(v.w, 0.f);
      }
      u16x4 p = { f2bf(v.x), f2bf(v.y), f2bf(v.z), f2bf(v.w) };
      int byte = r * (BK * 2) + ((c4 * 8) ^ ((r & 7) << 4));
      *reinterpret_cast<u16x4*>(asb + byte) = p;
    }
#pragma unroll
    for (int i = 0; i < B_PER_T; ++i) {
      int chunk = tid + i * 256;
      int n = chunk >> 3, c = chunk & 7;
      int byte = n * (BK * 2) + ((c * 16) ^ ((n & 7) << 4));
      *reinterpret_cast<uint4*>(bsb + byte) = breg[i];
    }
    __syncthreads();
    if (t + 1 < nT) load_tiles((t + 1) * BK);

    bf16x8 af[FM][KSUB], bfr[FN][KSUB];
#pragma unroll
    for (int fm = 0; fm < FM; ++fm)
#pragma unroll
      for (int kk = 0; kk < KSUB; ++kk) {
        int row = wr * WM + fm * 16 + lr;
        int k = kk * 32 + lg * 8;
        int byte = row * (BK * 2) + ((k * 2) ^ ((row & 7) << 4));
        af[fm][kk] = *reinterpret_cast<const bf16x8*>(asb + byte);
      }
#pragma unroll
    for (int fn = 0; fn < FN; ++fn)
#pragma unroll
      for (int kk = 0; kk < KSUB; ++kk) {
        int n = wc * WN + fn * 16 + lr;
        int k = kk * 32 + lg * 8;
        int byte = n * (BK * 2) + ((k * 2) ^ ((n & 7) << 4));
        bfr[fn][kk] = *reinterpret_cast<const bf16x8*>(bsb + byte);
      }
#pragma unroll
    for (int kk = 0; kk < KSUB; ++kk)
#pragma unroll
      for (int fm = 0; fm < FM; ++fm)
#pragma unroll
        for (int fn = 0; fn < FN; ++fn)
          acc[fm][fn] = __builtin_amdgcn_mfma_f32_16x16x32_bf16(
              af[fm][kk], bfr[fn][kk], acc[fm][fn], 0, 0, 0);
  }

#pragma unroll
  for (int fm = 0; fm < FM; ++fm) {
#pragma unroll
    for (int fn = 0; fn < FN; ++fn) {
      int col = wc * WN + fn * 16 + lr;
#pragma unroll
      for (int j = 0; j < 4; ++j) {
        int row = blockM + wr * WM + fm * 16 + lg * 4 + j;
        if (row < M)
          Hb[(size_t)row * NC + col] = f2bf(acc[fm][fn][j]);
      }
    }
  }
}

// ---------------- CSR aggregation: wave per node, no atomics ----------------
// out[n][c] = bias[c] + h[n][c]*dinv[n]^2 + sum_e h[src_e][c]*nrm_e
__global__ void agg_csr128_k(const int* __restrict__ row, const uint2* __restrict__ eadj,
                             const unsigned short* __restrict__ h, const float* __restrict__ bias,
                             const float* __restrict__ dinv, float* __restrict__ out, int N) {
  const int lane = threadIdx.x & 63;
  const int node = blockIdx.x * (blockDim.x >> 6) + (threadIdx.x >> 6);
  if (node >= N) return;
  const int beg = row[node], end = row[node + 1];
  const float di = dinv[node];
  unsigned int hv = *reinterpret_cast<const unsigned int*>(h + (size_t)node * 128 + lane * 2);
  float acc0 = bflo(hv) * di * di;
  float acc1 = bfhi(hv) * di * di;
  int e = beg;
  for (; e + 2 <= end; e += 2) {
    uint2 m0 = eadj[e], m1 = eadj[e + 1];
    int s0 = __builtin_amdgcn_readfirstlane(m0.x);
    int s1 = __builtin_amdgcn_readfirstlane(m1.x);
    float n0 = __builtin_bit_cast(float, __builtin_amdgcn_readfirstlane(m0.y));
    float n1 = __builtin_bit_cast(float, __builtin_amdgcn_readfirstlane(m1.y));
    unsigned int h0 = *reinterpret_cast<const unsigned int*>(h + (size_t)s0 * 128 + lane * 2);
    unsigned int h1 = *reinterpret_cast<const unsigned int*>(h + (size_t)s1 * 128 + lane * 2);
    acc0 += bflo(h0) * n0 + bflo(h1) * n1;
    acc1 += bfhi(h0) * n0 + bfhi(h1) * n1;
  }
  if (e < end) {
    uint2 m0 = eadj[e];
    int s0 = __builtin_amdgcn_readfirstlane(m0.x);
    float n0 = __builtin_bit_cast(float, __builtin_amdgcn_readfirstlane(m0.y));
    unsigned int h0 = *reinterpret_cast<const unsigned int*>(h + (size_t)s0 * 128 + lane * 2);
    acc0 += bflo(h0) * n0;
    acc1 += bfhi(h0) * n0;
  }
  float2 b = *reinterpret_cast<const float2*>(bias + lane * 2);
  float2 o = { acc0 + b.x, acc1 + b.y };
  *reinterpret_cast<float2*>(out + (size_t)node * 128 + lane * 2) = o;
}

// D=64: two half-waves each take alternating edges; combine via shfl_xor(32)
__global__ void agg_csr64_k(const int* __restrict__ row, const uint2* __restrict__ eadj,
                            const unsigned short* __restrict__ h, const float* __restrict__ bias,
                            const float* __restrict__ dinv, float* __restrict__ out, int N) {
  const int lane = threadIdx.x & 63;
  const int half = lane >> 5;
  const int l = lane & 31;
  const int node = blockIdx.x * (blockDim.x >> 6) + (threadIdx.x >> 6);
  if (node >= N) return;
  const int beg = row[node], end = row[node + 1];
  float acc0 = 0.f, acc1 = 0.f;
  if (half == 0) {
    const float di = dinv[node];
    unsigned int hv = *reinterpret_cast<const unsigned int*>(h + (size_t)node * 64 + l * 2);
    acc0 = bflo(hv) * di * di;
    acc1 = bfhi(hv) * di * di;
  }
  for (int e = beg + half; e < end; e += 2) {
    uint2 m = eadj[e];
    int s = m.x;
    float nm = __builtin_bit_cast(float, m.y);
    unsigned int hv = *reinterpret_cast<const unsigned int*>(h + (size_t)s * 64 + l * 2);
    acc0 += bflo(hv) * nm;
    acc1 += bfhi(hv) * nm;
  }
  acc0 += __shfl_xor(acc0, 32, 64);
  acc1 += __shfl_xor(acc1, 32, 64);
  if (half == 0) {
    float2 b = *reinterpret_cast<const float2*>(bias + l * 2);
    float2 o = { acc0 + b.x, acc1 + b.y };
    *reinterpret_cast<float2*>(out + (size_t)node * 64 + l * 2) = o;
  }
}

// D=1: thread per node
__global__ void agg_csr1_k(const int* __restrict__ row, const uint2* __restrict__ eadj,
                           const float* __restrict__ h3, const float* __restrict__ b3,
                           const float* __restrict__ dinv, float* __restrict__ out, int N) {
  int n = blockIdx.x * blockDim.x + threadIdx.x;
  if (n >= N) return;
  float di = dinv[n];
  float acc = h3[n] * di * di;
  int end = row[n + 1];
  for (int e = row[n]; e < end; ++e) {
    uint2 m = eadj[e];
    acc += h3[m.x] * __builtin_bit_cast(float, m.y);
  }
  out[n] = acc + b3[0];
}

// ---------------- layer-3 GEMV (D=64 -> 1), relu fused ----------------
__global__ void gemv3_k(const float* __restrict__ o2, const float* __restrict__ W3,
                        float* __restrict__ h3, int M) {
  int lane = threadIdx.x & 63;
  int r = blockIdx.x * (blockDim.x >> 6) + (threadIdx.x >> 6);
  if (r >= M) return;
  float v = fmaxf(o2[(size_t)r * 64 + lane], 0.f) * W3[lane];
#pragma unroll
  for (int off = 32; off > 0; off >>= 1) v += __shfl_xor(v, off, 64);
  if (lane == 0) h3[r] = v;
}

// ---------------- launch ----------------
extern "C" void kernel_launch(void* const* d_in, const int* in_sizes, int n_in,
                              void* d_out, int out_size, void* d_ws, size_t ws_size,
                              hipStream_t stream) {
  const float* x  = (const float*)d_in[0];
  const int*   ei = (const int*)d_in[1];
  const float* ea = (const float*)d_in[2];
  const float* W1 = (const float*)d_in[3];
  const float* b1 = (const float*)d_in[4];
  const float* W2 = (const float*)d_in[5];
  const float* b2 = (const float*)d_in[6];
  const float* W3 = (const float*)d_in[7];
  const float* b3 = (const float*)d_in[8];
  float* out = (float*)d_out;

  const int N = in_sizes[0] / 512;  // 100000
  const int E = in_sizes[2];        // 1600000
  const int* src = ei;
  const int* dst = ei + E;

  char* w = (char*)d_ws;
  auto alloc = [&](size_t bytes) {
    char* p = w; w += (bytes + 511) & ~(size_t)511; return p;
  };
  float* dinv         = (float*)alloc((size_t)N * 4);
  int*   cnt          = (int*)alloc((size_t)N * 4);
  int*   rowp         = (int*)alloc((size_t)(N + 1) * 4);
  int*   bsum         = (int*)alloc(4096 * 4);
  int*   cur          = (int*)alloc((size_t)N * 4);
  uint2* eadj         = (uint2*)alloc((size_t)E * 8);
  unsigned short* h1  = (unsigned short*)alloc((size_t)N * 128 * 2);
  float* o1           = (float*)alloc((size_t)N * 128 * 4);
  unsigned short* h2  = (unsigned short*)alloc((size_t)N * 64 * 2);
  float* o2           = (float*)alloc((size_t)N * 64 * 4);
  float* h3           = (float*)alloc((size_t)N * 4);
  unsigned short* wt1 = (unsigned short*)alloc(512 * 128 * 2);
  unsigned short* wt2 = (unsigned short*)alloc(128 * 64 * 2);

  const int TB = 256;
  const int nb_scan = (N + 2047) / 2048;

  hipMemsetAsync(cnt, 0, (size_t)N * 4, stream);
  hipMemsetAsync(cur, 0, (size_t)N * 4, stream);

  // degree + counts
  fill_deg_k<<<(N + TB - 1) / TB, TB, 0, stream>>>(dinv, N);
  edge_prep_k<<<(E + TB - 1) / TB, TB, 0, stream>>>(dst, ea, dinv, cnt, E);
  rsqrt_inplace_k<<<(N + TB - 1) / TB, TB, 0, stream>>>(dinv, N);
  // CSR build
  scan1_k<<<nb_scan, 256, 0, stream>>>(cnt, rowp, bsum, N);
  scan2_k<<<1, 64, 0, stream>>>(bsum, nb_scan);
  scan3_k<<<(N + 1 + TB - 1) / TB, TB, 0, stream>>>(rowp, bsum, N, E);
  scatter_k<<<(E + TB - 1) / TB, TB, 0, stream>>>(src, dst, ea, dinv, rowp, cur, eadj, E);
  // weights
  conv_wt_k<<<(512 * 128 + TB - 1) / TB, TB, 0, stream>>>(W1, wt1, 512, 128);
  conv_wt_k<<<(128 * 64 + TB - 1) / TB, TB, 0, stream>>>(W2, wt2, 128, 64);

  const int gblocks = (N + 127) / 128;
  const int ablocks = (N + 3) / 4;
  // layer 1
  gemm_k<128, 512, false><<<gblocks, TB, 0, stream>>>(x, wt1, h1, N);
  agg_csr128_k<<<ablocks, TB, 0, stream>>>(rowp, eadj, h1, b1, dinv, o1, N);
  // layer 2 (relu fused into gemm A-load)
  gemm_k<64, 128, true><<<gblocks, TB, 0, stream>>>(o1, wt2, h2, N);
  agg_csr64_k<<<ablocks, TB, 0, stream>>>(rowp, eadj, h2, b2, dinv, o2, N);
  // layer 3
  gemv3_k<<<ablocks, TB, 0, stream>>>(o2, W3, h3, N);
  agg_csr1_k<<<(N + TB - 1) / TB, TB, 0, stream>>>(rowp, eadj, h3, b3, dinv, out, N);
}

// Round 3
// 713.102 us; speedup vs baseline: 2.1668x; 1.1308x over previous
//
#include <hip/hip_runtime.h>

typedef __attribute__((ext_vector_type(4))) float f32x4;
typedef __attribute__((ext_vector_type(8))) short bf16x8;
typedef __attribute__((ext_vector_type(4))) unsigned short u16x4;

__device__ __forceinline__ unsigned short f2bf(float f) {
  unsigned int u = __builtin_bit_cast(unsigned int, f);
  u += 0x7fffu + ((u >> 16) & 1u);   // round-to-nearest-even
  return (unsigned short)(u >> 16);
}
__device__ __forceinline__ float bf2f(unsigned short h) {
  unsigned int u = ((unsigned int)h) << 16;
  return __builtin_bit_cast(float, u);
}
__device__ __forceinline__ float bflo(unsigned int u) { return bf2f((unsigned short)(u & 0xffffu)); }
__device__ __forceinline__ float bfhi(unsigned int u) { return bf2f((unsigned short)(u >> 16)); }

// ---------------- CSR build ----------------
// one atomic per edge: returned old count == within-bucket rank
__global__ void hist_rank_k(const int* __restrict__ dst, int* __restrict__ cnt,
                            int* __restrict__ rank, int E) {
  int e = blockIdx.x * blockDim.x + threadIdx.x;
  if (e < E) rank[e] = atomicAdd(&cnt[dst[e]], 1);
}

__global__ void scan1_k(const int* __restrict__ cnt, int* __restrict__ row,
                        int* __restrict__ bsum, int N) {
  __shared__ int sh[256];
  const int tid = threadIdx.x;
  const int base = blockIdx.x * 2048 + tid * 8;
  int v[8]; int s = 0;
#pragma unroll
  for (int i = 0; i < 8; ++i) {
    int idx = base + i;
    v[i] = (idx < N) ? cnt[idx] : 0;
    s += v[i];
  }
  sh[tid] = s;
  __syncthreads();
  for (int off = 1; off < 256; off <<= 1) {
    int t = (tid >= off) ? sh[tid - off] : 0;
    __syncthreads();
    sh[tid] += t;
    __syncthreads();
  }
  int excl = sh[tid] - s;
  if (tid == 255) bsum[blockIdx.x] = sh[255];
  int run = excl;
#pragma unroll
  for (int i = 0; i < 8; ++i) {
    int idx = base + i;
    if (idx < N) row[idx] = run;
    run += v[i];
  }
}
__global__ void scan2_k(int* __restrict__ bsum, int nb) {
  if (threadIdx.x == 0 && blockIdx.x == 0) {
    int run = 0;
    for (int i = 0; i < nb; ++i) { int t = bsum[i]; bsum[i] = run; run += t; }
  }
}
__global__ void scan3_k(int* __restrict__ row, const int* __restrict__ bsum, int N, int E) {
  int idx = blockIdx.x * blockDim.x + threadIdx.x;
  if (idx < N) row[idx] += bsum[idx >> 11];
  if (idx == N) row[N] = E;
}
// atomic-free scatter: pos = row[dst] + rank. Stores (src, raw ew).
__global__ void scatter_nr_k(const int* __restrict__ src, const int* __restrict__ dst,
                             const float* __restrict__ ew, const int* __restrict__ row,
                             const int* __restrict__ rank, uint2* __restrict__ eadj, int E) {
  int e = blockIdx.x * blockDim.x + threadIdx.x;
  if (e >= E) return;
  int pos = row[dst[e]] + rank[e];
  eadj[pos] = make_uint2((unsigned)src[e], __builtin_bit_cast(unsigned, ew[e]));
}
// weighted in-degree from sorted CSR (no atomics), dinv = rsqrt(1 + sum ew)
__global__ void deg_dinv_k(const int* __restrict__ row, const uint2* __restrict__ eadj,
                           float* __restrict__ dinv, int N) {
  int n = blockIdx.x * blockDim.x + threadIdx.x;
  if (n >= N) return;
  float s = 1.0f;  // self-loop weight
  int end = row[n + 1];
  for (int e = row[n]; e < end; ++e) s += __builtin_bit_cast(float, eadj[e].y);
  dinv[n] = rsqrtf(s);
}
// rewrite eadj.y = ew * dinv[src] * dinv[dst]
__global__ void fixnorm_k(const int* __restrict__ row, uint2* __restrict__ eadj,
                          const float* __restrict__ dinv, int N) {
  int n = blockIdx.x * blockDim.x + threadIdx.x;
  if (n >= N) return;
  float dd = dinv[n];
  int end = row[n + 1];
  for (int e = row[n]; e < end; ++e) {
    uint2 m = eadj[e];
    float nm = __builtin_bit_cast(float, m.y) * dinv[m.x] * dd;
    eadj[e].y = __builtin_bit_cast(unsigned, nm);
  }
}
// both weight matrices -> bf16 transposed, one launch
__global__ void conv_wt2_k(const float* __restrict__ W1, unsigned short* __restrict__ Wt1,
                           const float* __restrict__ W2, unsigned short* __restrict__ Wt2) {
  int idx = blockIdx.x * blockDim.x + threadIdx.x;
  if (idx < 512 * 128) {
    int n = idx >> 9, k = idx & 511;               // Wt1[n][k] = W1[k][n], K=512,N=128
    Wt1[idx] = f2bf(W1[k * 128 + n]);
  } else {
    int j = idx - 512 * 128;
    if (j < 128 * 64) {
      int n = j >> 7, k = j & 127;                 // Wt2[n][k] = W2[k][n], K=128,N=64
      Wt2[j] = f2bf(W2[k * 64 + n]);
    }
  }
}

// ---------------- bf16 MFMA GEMM (writes Hb bf16 only) ----------------
template<int NC, int KD, bool RELU>
__launch_bounds__(256, 2)
__global__ void gemm_k(const float* __restrict__ A, const unsigned short* __restrict__ Wt,
                       unsigned short* __restrict__ Hb, int M) {
  constexpr int BM = 128, BK = 64;
  constexpr int WN = 64;
  constexpr int WGN = NC / WN;
  constexpr int WGM = 4 / WGN;
  constexpr int WM = BM / WGM;
  constexpr int FM = WM / 16;
  constexpr int FN = WN / 16;
  constexpr int KSUB = BK / 32;
  constexpr int A_PER_T = BM * (BK / 4) / 256;
  constexpr int B_PER_T = NC * (BK / 8) / 256;
  constexpr int nT = KD / BK;

  __shared__ unsigned short As[BM * BK];
  __shared__ unsigned short Bs[NC * BK];
  char* asb = reinterpret_cast<char*>(As);
  char* bsb = reinterpret_cast<char*>(Bs);

  const int tid = threadIdx.x;
  const int lane = tid & 63;
  const int wid = tid >> 6;
  const int wr = wid / WGN;
  const int wc = wid % WGN;
  const int lg = lane >> 4;
  const int lr = lane & 15;
  const int blockM = blockIdx.x * BM;

  float4 areg[A_PER_T];
  uint4 breg[B_PER_T];

  auto load_tiles = [&](int k0) {
#pragma unroll
    for (int i = 0; i < A_PER_T; ++i) {
      int chunk = tid + i * 256;
      int r = chunk >> 4, c4 = chunk & 15;
      int gr = blockM + r; if (gr >= M) gr = M - 1;
      areg[i] = *reinterpret_cast<const float4*>(A + (size_t)gr * KD + k0 + c4 * 4);
    }
#pragma unroll
    for (int i = 0; i < B_PER_T; ++i) {
      int chunk = tid + i * 256;
      int n = chunk >> 3, c = chunk & 7;
      breg[i] = *reinterpret_cast<const uint4*>(Wt + (size_t)n * KD + k0 + c * 8);
    }
  };

  f32x4 acc[FM][FN] = {};
  load_tiles(0);

  for (int t = 0; t < nT; ++t) {
    __syncthreads();
#pragma unroll
    for (int i = 0; i < A_PER_T; ++i) {
      int chunk = tid + i * 256;
      int r = chunk >> 4, c4 = chunk & 15;
      float4 v = areg[i];
      if (RELU) {
        v.x = fmaxf(v.x, 0.f); v.y = fmaxf(v.y, 0.f);
        v.z = fmaxf(v.z, 0.f); v.w = fmaxf(v.w, 0.f);
      }
      u16x4 p = { f2bf(v.x), f2bf(v.y), f2bf(v.z), f2bf(v.w) };
      int byte = r * (BK * 2) + ((c4 * 8) ^ ((r & 7) << 4));
      *reinterpret_cast<u16x4*>(asb + byte) = p;
    }
#pragma unroll
    for (int i = 0; i < B_PER_T; ++i) {
      int chunk = tid + i * 256;
      int n = chunk >> 3, c = chunk & 7;
      int byte = n * (BK * 2) + ((c * 16) ^ ((n & 7) << 4));
      *reinterpret_cast<uint4*>(bsb + byte) = breg[i];
    }
    __syncthreads();
    if (t + 1 < nT) load_tiles((t + 1) * BK);

    bf16x8 af[FM][KSUB], bfr[FN][KSUB];
#pragma unroll
    for (int fm = 0; fm < FM; ++fm)
#pragma unroll
      for (int kk = 0; kk < KSUB; ++kk) {
        int row = wr * WM + fm * 16 + lr;
        int k = kk * 32 + lg * 8;
        int byte = row * (BK * 2) + ((k * 2) ^ ((row & 7) << 4));
        af[fm][kk] = *reinterpret_cast<const bf16x8*>(asb + byte);
      }
#pragma unroll
    for (int fn = 0; fn < FN; ++fn)
#pragma unroll
      for (int kk = 0; kk < KSUB; ++kk) {
        int n = wc * WN + fn * 16 + lr;
        int k = kk * 32 + lg * 8;
        int byte = n * (BK * 2) + ((k * 2) ^ ((n & 7) << 4));
        bfr[fn][kk] = *reinterpret_cast<const bf16x8*>(bsb + byte);
      }
#pragma unroll
    for (int kk = 0; kk < KSUB; ++kk)
#pragma unroll
      for (int fm = 0; fm < FM; ++fm)
#pragma unroll
        for (int fn = 0; fn < FN; ++fn)
          acc[fm][fn] = __builtin_amdgcn_mfma_f32_16x16x32_bf16(
              af[fm][kk], bfr[fn][kk], acc[fm][fn], 0, 0, 0);
  }

#pragma unroll
  for (int fm = 0; fm < FM; ++fm) {
#pragma unroll
    for (int fn = 0; fn < FN; ++fn) {
      int col = wc * WN + fn * 16 + lr;
#pragma unroll
      for (int j = 0; j < 4; ++j) {
        int row = blockM + wr * WM + fm * 16 + lg * 4 + j;
        if (row < M)
          Hb[(size_t)row * NC + col] = f2bf(acc[fm][fn][j]);
      }
    }
  }
}

// ---------------- CSR aggregation: wave per node, no atomics ----------------
__global__ void agg_csr128_k(const int* __restrict__ row, const uint2* __restrict__ eadj,
                             const unsigned short* __restrict__ h, const float* __restrict__ bias,
                             const float* __restrict__ dinv, float* __restrict__ out, int N) {
  const int lane = threadIdx.x & 63;
  const int node = blockIdx.x * (blockDim.x >> 6) + (threadIdx.x >> 6);
  if (node >= N) return;
  const int beg = row[node], end = row[node + 1];
  const float di = dinv[node];
  unsigned int hv = *reinterpret_cast<const unsigned int*>(h + (size_t)node * 128 + lane * 2);
  float acc0 = bflo(hv) * di * di;
  float acc1 = bfhi(hv) * di * di;
  int e = beg;
  for (; e + 2 <= end; e += 2) {
    uint2 m0 = eadj[e], m1 = eadj[e + 1];
    int s0 = __builtin_amdgcn_readfirstlane(m0.x);
    int s1 = __builtin_amdgcn_readfirstlane(m1.x);
    float n0 = __builtin_bit_cast(float, __builtin_amdgcn_readfirstlane(m0.y));
    float n1 = __builtin_bit_cast(float, __builtin_amdgcn_readfirstlane(m1.y));
    unsigned int h0 = *reinterpret_cast<const unsigned int*>(h + (size_t)s0 * 128 + lane * 2);
    unsigned int h1 = *reinterpret_cast<const unsigned int*>(h + (size_t)s1 * 128 + lane * 2);
    acc0 += bflo(h0) * n0 + bflo(h1) * n1;
    acc1 += bfhi(h0) * n0 + bfhi(h1) * n1;
  }
  if (e < end) {
    uint2 m0 = eadj[e];
    int s0 = __builtin_amdgcn_readfirstlane(m0.x);
    float n0 = __builtin_bit_cast(float, __builtin_amdgcn_readfirstlane(m0.y));
    unsigned int h0 = *reinterpret_cast<const unsigned int*>(h + (size_t)s0 * 128 + lane * 2);
    acc0 += bflo(h0) * n0;
    acc1 += bfhi(h0) * n0;
  }
  float2 b = *reinterpret_cast<const float2*>(bias + lane * 2);
  float2 o = { acc0 + b.x, acc1 + b.y };
  *reinterpret_cast<float2*>(out + (size_t)node * 128 + lane * 2) = o;
}

// D=64: two half-waves take alternating edges; combine via shfl_xor(32)
__global__ void agg_csr64_k(const int* __restrict__ row, const uint2* __restrict__ eadj,
                            const unsigned short* __restrict__ h, const float* __restrict__ bias,
                            const float* __restrict__ dinv, float* __restrict__ out, int N) {
  const int lane = threadIdx.x & 63;
  const int half = lane >> 5;
  const int l = lane & 31;
  const int node = blockIdx.x * (blockDim.x >> 6) + (threadIdx.x >> 6);
  if (node >= N) return;
  const int beg = row[node], end = row[node + 1];
  float acc0 = 0.f, acc1 = 0.f;
  if (half == 0) {
    const float di = dinv[node];
    unsigned int hv = *reinterpret_cast<const unsigned int*>(h + (size_t)node * 64 + l * 2);
    acc0 = bflo(hv) * di * di;
    acc1 = bfhi(hv) * di * di;
  }
  for (int e = beg + half; e < end; e += 2) {
    uint2 m = eadj[e];
    int s = m.x;
    float nm = __builtin_bit_cast(float, m.y);
    unsigned int hv = *reinterpret_cast<const unsigned int*>(h + (size_t)s * 64 + l * 2);
    acc0 += bflo(hv) * nm;
    acc1 += bfhi(hv) * nm;
  }
  acc0 += __shfl_xor(acc0, 32, 64);
  acc1 += __shfl_xor(acc1, 32, 64);
  if (half == 0) {
    float2 b = *reinterpret_cast<const float2*>(bias + l * 2);
    float2 o = { acc0 + b.x, acc1 + b.y };
    *reinterpret_cast<float2*>(out + (size_t)node * 64 + l * 2) = o;
  }
}

// D=1: thread per node
__global__ void agg_csr1_k(const int* __restrict__ row, const uint2* __restrict__ eadj,
                           const float* __restrict__ h3, const float* __restrict__ b3,
                           const float* __restrict__ dinv, float* __restrict__ out, int N) {
  int n = blockIdx.x * blockDim.x + threadIdx.x;
  if (n >= N) return;
  float di = dinv[n];
  float acc = h3[n] * di * di;
  int end = row[n + 1];
  for (int e = row[n]; e < end; ++e) {
    uint2 m = eadj[e];
    acc += h3[m.x] * __builtin_bit_cast(float, m.y);
  }
  out[n] = acc + b3[0];
}

// ---------------- layer-3 GEMV (D=64 -> 1), relu fused ----------------
__global__ void gemv3_k(const float* __restrict__ o2, const float* __restrict__ W3,
                        float* __restrict__ h3, int M) {
  int lane = threadIdx.x & 63;
  int r = blockIdx.x * (blockDim.x >> 6) + (threadIdx.x >> 6);
  if (r >= M) return;
  float v = fmaxf(o2[(size_t)r * 64 + lane], 0.f) * W3[lane];
#pragma unroll
  for (int off = 32; off > 0; off >>= 1) v += __shfl_xor(v, off, 64);
  if (lane == 0) h3[r] = v;
}

// ---------------- launch ----------------
extern "C" void kernel_launch(void* const* d_in, const int* in_sizes, int n_in,
                              void* d_out, int out_size, void* d_ws, size_t ws_size,
                              hipStream_t stream) {
  const float* x  = (const float*)d_in[0];
  const int*   ei = (const int*)d_in[1];
  const float* ea = (const float*)d_in[2];
  const float* W1 = (const float*)d_in[3];
  const float* b1 = (const float*)d_in[4];
  const float* W2 = (const float*)d_in[5];
  const float* b2 = (const float*)d_in[6];
  const float* W3 = (const float*)d_in[7];
  const float* b3 = (const float*)d_in[8];
  float* out = (float*)d_out;

  const int N = in_sizes[0] / 512;  // 100000
  const int E = in_sizes[2];        // 1600000
  const int* src = ei;
  const int* dst = ei + E;

  char* w = (char*)d_ws;
  auto alloc = [&](size_t bytes) {
    char* p = w; w += (bytes + 511) & ~(size_t)511; return p;
  };
  float* dinv         = (float*)alloc((size_t)N * 4);
  int*   cnt          = (int*)alloc((size_t)N * 4);
  int*   rowp         = (int*)alloc((size_t)(N + 1) * 4);
  int*   bsum         = (int*)alloc(4096 * 4);
  int*   rank         = (int*)alloc((size_t)E * 4);
  uint2* eadj         = (uint2*)alloc((size_t)E * 8);
  unsigned short* h1  = (unsigned short*)alloc((size_t)N * 128 * 2);
  float* o1           = (float*)alloc((size_t)N * 128 * 4);
  unsigned short* h2  = (unsigned short*)alloc((size_t)N * 64 * 2);
  float* o2           = (float*)alloc((size_t)N * 64 * 4);
  float* h3           = (float*)alloc((size_t)N * 4);
  unsigned short* wt1 = (unsigned short*)alloc(512 * 128 * 2);
  unsigned short* wt2 = (unsigned short*)alloc(128 * 64 * 2);

  const int TB = 256;
  const int nb_scan = (N + 2047) / 2048;

  hipMemsetAsync(cnt, 0, (size_t)N * 4, stream);

  // CSR build: hist(+rank) -> scan -> scatter (atomic-free) -> deg/dinv -> norms
  hist_rank_k<<<(E + TB - 1) / TB, TB, 0, stream>>>(dst, cnt, rank, E);
  scan1_k<<<nb_scan, 256, 0, stream>>>(cnt, rowp, bsum, N);
  scan2_k<<<1, 64, 0, stream>>>(bsum, nb_scan);
  scan3_k<<<(N + 1 + TB - 1) / TB, TB, 0, stream>>>(rowp, bsum, N, E);
  scatter_nr_k<<<(E + TB - 1) / TB, TB, 0, stream>>>(src, dst, ea, rowp, rank, eadj, E);
  deg_dinv_k<<<(N + TB - 1) / TB, TB, 0, stream>>>(rowp, eadj, dinv, N);
  fixnorm_k<<<(N + TB - 1) / TB, TB, 0, stream>>>(rowp, eadj, dinv, N);
  conv_wt2_k<<<(512 * 128 + 128 * 64 + TB - 1) / TB, TB, 0, stream>>>(W1, wt1, W2, wt2);

  const int gblocks = (N + 127) / 128;
  const int ablocks = (N + 3) / 4;
  // layer 1
  gemm_k<128, 512, false><<<gblocks, TB, 0, stream>>>(x, wt1, h1, N);
  agg_csr128_k<<<ablocks, TB, 0, stream>>>(rowp, eadj, h1, b1, dinv, o1, N);
  // layer 2 (relu fused into gemm A-load)
  gemm_k<64, 128, true><<<gblocks, TB, 0, stream>>>(o1, wt2, h2, N);
  agg_csr64_k<<<ablocks, TB, 0, stream>>>(rowp, eadj, h2, b2, dinv, o2, N);
  // layer 3
  gemv3_k<<<ablocks, TB, 0, stream>>>(o2, W3, h3, N);
  agg_csr1_k<<<(N + TB - 1) / TB, TB, 0, stream>>>(rowp, eadj, h3, b3, dinv, out, N);
}

// Round 4
// 660.675 us; speedup vs baseline: 2.3388x; 1.0794x over previous
//
#include <hip/hip_runtime.h>

typedef __attribute__((ext_vector_type(4))) float f32x4;
typedef __attribute__((ext_vector_type(8))) short bf16x8;
typedef __attribute__((ext_vector_type(4))) unsigned short u16x4;

__device__ __forceinline__ unsigned short f2bf(float f) {
  unsigned int u = __builtin_bit_cast(unsigned int, f);
  u += 0x7fffu + ((u >> 16) & 1u);   // round-to-nearest-even
  return (unsigned short)(u >> 16);
}
__device__ __forceinline__ float bf2f(unsigned short h) {
  unsigned int u = ((unsigned int)h) << 16;
  return __builtin_bit_cast(float, u);
}
__device__ __forceinline__ float bflo(unsigned int u) { return bf2f((unsigned short)(u & 0xffffu)); }
__device__ __forceinline__ float bfhi(unsigned int u) { return bf2f((unsigned short)(u >> 16)); }
__device__ __forceinline__ unsigned int packbf(float a, float b) {
  return (unsigned int)f2bf(a) | ((unsigned int)f2bf(b) << 16);
}

// ---------------- CSR build ----------------
// one atomic per edge: returned old count == within-bucket rank
__global__ void hist_rank_k(const int* __restrict__ dst, int* __restrict__ cnt,
                            int* __restrict__ rank, int E) {
  int e = blockIdx.x * blockDim.x + threadIdx.x;
  if (e < E) rank[e] = atomicAdd(&cnt[dst[e]], 1);
}

__global__ void scan1_k(const int* __restrict__ cnt, int* __restrict__ row,
                        int* __restrict__ bsum, int N) {
  __shared__ int sh[256];
  const int tid = threadIdx.x;
  const int base = blockIdx.x * 2048 + tid * 8;
  int v[8]; int s = 0;
#pragma unroll
  for (int i = 0; i < 8; ++i) {
    int idx = base + i;
    v[i] = (idx < N) ? cnt[idx] : 0;
    s += v[i];
  }
  sh[tid] = s;
  __syncthreads();
  for (int off = 1; off < 256; off <<= 1) {
    int t = (tid >= off) ? sh[tid - off] : 0;
    __syncthreads();
    sh[tid] += t;
    __syncthreads();
  }
  int excl = sh[tid] - s;
  if (tid == 255) bsum[blockIdx.x] = sh[255];
  int run = excl;
#pragma unroll
  for (int i = 0; i < 8; ++i) {
    int idx = base + i;
    if (idx < N) row[idx] = run;
    run += v[i];
  }
}
__global__ void scan2_k(int* __restrict__ bsum, int nb) {
  if (threadIdx.x == 0 && blockIdx.x == 0) {
    int run = 0;
    for (int i = 0; i < nb; ++i) { int t = bsum[i]; bsum[i] = run; run += t; }
  }
}
__global__ void scan3_k(int* __restrict__ row, const int* __restrict__ bsum, int N, int E) {
  int idx = blockIdx.x * blockDim.x + threadIdx.x;
  if (idx < N) row[idx] += bsum[idx >> 11];
  if (idx == N) row[N] = E;
}
// atomic-free scatter: pos = row[dst] + rank. Stores (src, raw ew).
__global__ void scatter_nr_k(const int* __restrict__ src, const int* __restrict__ dst,
                             const float* __restrict__ ew, const int* __restrict__ row,
                             const int* __restrict__ rank, uint2* __restrict__ eadj, int E) {
  int e = blockIdx.x * blockDim.x + threadIdx.x;
  if (e >= E) return;
  int pos = row[dst[e]] + rank[e];
  eadj[pos] = make_uint2((unsigned)src[e], __builtin_bit_cast(unsigned, ew[e]));
}
// weighted in-degree from sorted CSR (no atomics), dinv = rsqrt(1 + sum ew)
__global__ void deg_dinv_k(const int* __restrict__ row, const uint2* __restrict__ eadj,
                           float* __restrict__ dinv, int N) {
  int n = blockIdx.x * blockDim.x + threadIdx.x;
  if (n >= N) return;
  float s = 1.0f;  // self-loop weight
  int end = row[n + 1];
  for (int e = row[n]; e < end; ++e) s += __builtin_bit_cast(float, eadj[e].y);
  dinv[n] = rsqrtf(s);
}
// rewrite eadj.y = ew * dinv[src] * dinv[dst]
__global__ void fixnorm_k(const int* __restrict__ row, uint2* __restrict__ eadj,
                          const float* __restrict__ dinv, int N) {
  int n = blockIdx.x * blockDim.x + threadIdx.x;
  if (n >= N) return;
  float dd = dinv[n];
  int end = row[n + 1];
  for (int e = row[n]; e < end; ++e) {
    uint2 m = eadj[e];
    float nm = __builtin_bit_cast(float, m.y) * dinv[m.x] * dd;
    eadj[e].y = __builtin_bit_cast(unsigned, nm);
  }
}
// both weight matrices -> bf16 transposed, one launch
__global__ void conv_wt2_k(const float* __restrict__ W1, unsigned short* __restrict__ Wt1,
                           const float* __restrict__ W2, unsigned short* __restrict__ Wt2) {
  int idx = blockIdx.x * blockDim.x + threadIdx.x;
  if (idx < 512 * 128) {
    int n = idx >> 9, k = idx & 511;               // Wt1[n][k] = W1[k][n]
    Wt1[idx] = f2bf(W1[k * 128 + n]);
  } else {
    int j = idx - 512 * 128;
    if (j < 128 * 64) {
      int n = j >> 7, k = j & 127;                 // Wt2[n][k] = W2[k][n]
      Wt2[j] = f2bf(W2[k * 64 + n]);
    }
  }
}

// ---------------- layer-1 GEMM: A fp32, bf16 MFMA, writes h1 bf16 ----------------
template<int NC, int KD>
__launch_bounds__(256, 2)
__global__ void gemm_f32a_k(const float* __restrict__ A, const unsigned short* __restrict__ Wt,
                            unsigned short* __restrict__ Hb, int M) {
  constexpr int BM = 128, BK = 64;
  constexpr int WN = 64;
  constexpr int WGN = NC / WN;
  constexpr int WGM = 4 / WGN;
  constexpr int WM = BM / WGM;
  constexpr int FM = WM / 16;
  constexpr int FN = WN / 16;
  constexpr int KSUB = BK / 32;
  constexpr int A_PER_T = BM * (BK / 4) / 256;
  constexpr int B_PER_T = NC * (BK / 8) / 256;
  constexpr int nT = KD / BK;

  __shared__ unsigned short As[BM * BK];
  __shared__ unsigned short Bs[NC * BK];
  char* asb = reinterpret_cast<char*>(As);
  char* bsb = reinterpret_cast<char*>(Bs);

  const int tid = threadIdx.x;
  const int lane = tid & 63;
  const int wid = tid >> 6;
  const int wr = wid / WGN;
  const int wc = wid % WGN;
  const int lg = lane >> 4;
  const int lr = lane & 15;
  const int blockM = blockIdx.x * BM;

  float4 areg[A_PER_T];
  uint4 breg[B_PER_T];

  auto load_tiles = [&](int k0) {
#pragma unroll
    for (int i = 0; i < A_PER_T; ++i) {
      int chunk = tid + i * 256;
      int r = chunk >> 4, c4 = chunk & 15;
      int gr = blockM + r; if (gr >= M) gr = M - 1;
      areg[i] = *reinterpret_cast<const float4*>(A + (size_t)gr * KD + k0 + c4 * 4);
    }
#pragma unroll
    for (int i = 0; i < B_PER_T; ++i) {
      int chunk = tid + i * 256;
      int n = chunk >> 3, c = chunk & 7;
      breg[i] = *reinterpret_cast<const uint4*>(Wt + (size_t)n * KD + k0 + c * 8);
    }
  };

  f32x4 acc[FM][FN] = {};
  load_tiles(0);

  for (int t = 0; t < nT; ++t) {
    __syncthreads();
#pragma unroll
    for (int i = 0; i < A_PER_T; ++i) {
      int chunk = tid + i * 256;
      int r = chunk >> 4, c4 = chunk & 15;
      float4 v = areg[i];
      u16x4 p = { f2bf(v.x), f2bf(v.y), f2bf(v.z), f2bf(v.w) };
      int byte = r * (BK * 2) + ((c4 * 8) ^ ((r & 7) << 4));
      *reinterpret_cast<u16x4*>(asb + byte) = p;
    }
#pragma unroll
    for (int i = 0; i < B_PER_T; ++i) {
      int chunk = tid + i * 256;
      int n = chunk >> 3, c = chunk & 7;
      int byte = n * (BK * 2) + ((c * 16) ^ ((n & 7) << 4));
      *reinterpret_cast<uint4*>(bsb + byte) = breg[i];
    }
    __syncthreads();
    if (t + 1 < nT) load_tiles((t + 1) * BK);

    bf16x8 af[FM][KSUB], bfr[FN][KSUB];
#pragma unroll
    for (int fm = 0; fm < FM; ++fm)
#pragma unroll
      for (int kk = 0; kk < KSUB; ++kk) {
        int row = wr * WM + fm * 16 + lr;
        int k = kk * 32 + lg * 8;
        int byte = row * (BK * 2) + ((k * 2) ^ ((row & 7) << 4));
        af[fm][kk] = *reinterpret_cast<const bf16x8*>(asb + byte);
      }
#pragma unroll
    for (int fn = 0; fn < FN; ++fn)
#pragma unroll
      for (int kk = 0; kk < KSUB; ++kk) {
        int n = wc * WN + fn * 16 + lr;
        int k = kk * 32 + lg * 8;
        int byte = n * (BK * 2) + ((k * 2) ^ ((n & 7) << 4));
        bfr[fn][kk] = *reinterpret_cast<const bf16x8*>(bsb + byte);
      }
#pragma unroll
    for (int kk = 0; kk < KSUB; ++kk)
#pragma unroll
      for (int fm = 0; fm < FM; ++fm)
#pragma unroll
        for (int fn = 0; fn < FN; ++fn)
          acc[fm][fn] = __builtin_amdgcn_mfma_f32_16x16x32_bf16(
              af[fm][kk], bfr[fn][kk], acc[fm][fn], 0, 0, 0);
  }

#pragma unroll
  for (int fm = 0; fm < FM; ++fm)
#pragma unroll
    for (int fn = 0; fn < FN; ++fn) {
      int col = wc * WN + fn * 16 + lr;
#pragma unroll
      for (int j = 0; j < 4; ++j) {
        int row = blockM + wr * WM + fm * 16 + lg * 4 + j;
        if (row < M)
          Hb[(size_t)row * NC + col] = f2bf(acc[fm][fn][j]);
      }
    }
}

// ---------------- layer-2 GEMM: A bf16 (already relu'd), writes h2 bf16 ----------------
__launch_bounds__(256, 2)
__global__ void gemm_bf16a_k(const unsigned short* __restrict__ A,  // [M][128] bf16
                             const unsigned short* __restrict__ Wt, // [64][128] bf16
                             unsigned short* __restrict__ Hb, int M) {
  constexpr int BM = 128, BK = 64, NC = 64, KD = 128;
  constexpr int WM = 32;        // 4 waves along M
  constexpr int FM = 2, FN = 4, KSUB = 2;
  constexpr int A_PER_T = 4;    // 128*64*2B / 16B / 256
  constexpr int B_PER_T = 2;    // 64*64*2B / 16B / 256
  constexpr int nT = KD / BK;   // 2

  __shared__ unsigned short As[BM * BK];
  __shared__ unsigned short Bs[NC * BK];
  char* asb = reinterpret_cast<char*>(As);
  char* bsb = reinterpret_cast<char*>(Bs);

  const int tid = threadIdx.x;
  const int lane = tid & 63;
  const int wid = tid >> 6;
  const int lg = lane >> 4;
  const int lr = lane & 15;
  const int blockM = blockIdx.x * BM;

  uint4 areg[A_PER_T];
  uint4 breg[B_PER_T];

  auto load_tiles = [&](int k0) {
#pragma unroll
    for (int i = 0; i < A_PER_T; ++i) {
      int chunk = tid + i * 256;
      int r = chunk >> 3, c = chunk & 7;
      int gr = blockM + r; if (gr >= M) gr = M - 1;
      areg[i] = *reinterpret_cast<const uint4*>(A + (size_t)gr * KD + k0 + c * 8);
    }
#pragma unroll
    for (int i = 0; i < B_PER_T; ++i) {
      int chunk = tid + i * 256;
      int n = chunk >> 3, c = chunk & 7;
      breg[i] = *reinterpret_cast<const uint4*>(Wt + (size_t)n * KD + k0 + c * 8);
    }
  };

  f32x4 acc[FM][FN] = {};
  load_tiles(0);

  for (int t = 0; t < nT; ++t) {
    __syncthreads();
#pragma unroll
    for (int i = 0; i < A_PER_T; ++i) {
      int chunk = tid + i * 256;
      int r = chunk >> 3, c = chunk & 7;
      int byte = r * (BK * 2) + ((c * 16) ^ ((r & 7) << 4));
      *reinterpret_cast<uint4*>(asb + byte) = areg[i];
    }
#pragma unroll
    for (int i = 0; i < B_PER_T; ++i) {
      int chunk = tid + i * 256;
      int n = chunk >> 3, c = chunk & 7;
      int byte = n * (BK * 2) + ((c * 16) ^ ((n & 7) << 4));
      *reinterpret_cast<uint4*>(bsb + byte) = breg[i];
    }
    __syncthreads();
    if (t + 1 < nT) load_tiles((t + 1) * BK);

    bf16x8 af[FM][KSUB], bfr[FN][KSUB];
#pragma unroll
    for (int fm = 0; fm < FM; ++fm)
#pragma unroll
      for (int kk = 0; kk < KSUB; ++kk) {
        int row = wid * WM + fm * 16 + lr;
        int k = kk * 32 + lg * 8;
        int byte = row * (BK * 2) + ((k * 2) ^ ((row & 7) << 4));
        af[fm][kk] = *reinterpret_cast<const bf16x8*>(asb + byte);
      }
#pragma unroll
    for (int fn = 0; fn < FN; ++fn)
#pragma unroll
      for (int kk = 0; kk < KSUB; ++kk) {
        int n = fn * 16 + lr;
        int k = kk * 32 + lg * 8;
        int byte = n * (BK * 2) + ((k * 2) ^ ((n & 7) << 4));
        bfr[fn][kk] = *reinterpret_cast<const bf16x8*>(bsb + byte);
      }
#pragma unroll
    for (int kk = 0; kk < KSUB; ++kk)
#pragma unroll
      for (int fm = 0; fm < FM; ++fm)
#pragma unroll
        for (int fn = 0; fn < FN; ++fn)
          acc[fm][fn] = __builtin_amdgcn_mfma_f32_16x16x32_bf16(
              af[fm][kk], bfr[fn][kk], acc[fm][fn], 0, 0, 0);
  }

#pragma unroll
  for (int fm = 0; fm < FM; ++fm)
#pragma unroll
    for (int fn = 0; fn < FN; ++fn) {
      int col = fn * 16 + lr;
#pragma unroll
      for (int j = 0; j < 4; ++j) {
        int row = blockM + wid * WM + fm * 16 + lg * 4 + j;
        if (row < M)
          Hb[(size_t)row * NC + col] = f2bf(acc[fm][fn][j]);
      }
    }
}

// ---------------- layer-1 aggregation: wave per node; writes relu(o1+b1) as bf16 ----------------
__global__ void agg_csr128_k(const int* __restrict__ row, const uint2* __restrict__ eadj,
                             const unsigned short* __restrict__ h, const float* __restrict__ bias,
                             const float* __restrict__ dinv, unsigned int* __restrict__ o1b, int N) {
  const int lane = threadIdx.x & 63;
  const int node = blockIdx.x * (blockDim.x >> 6) + (threadIdx.x >> 6);
  if (node >= N) return;
  const unsigned int* hu = reinterpret_cast<const unsigned int*>(h);  // [N][64] pairs
  const int beg = row[node], end = row[node + 1];
  const float di = dinv[node];
  const float di2 = di * di;
  unsigned int hv = hu[(size_t)node * 64 + lane];
  float acc0 = bflo(hv) * di2;
  float acc1 = bfhi(hv) * di2;
  int e = beg;
  for (; e + 4 <= end; e += 4) {
    uint2 m0 = eadj[e], m1 = eadj[e + 1], m2 = eadj[e + 2], m3 = eadj[e + 3];
    int s0 = __builtin_amdgcn_readfirstlane(m0.x);
    int s1 = __builtin_amdgcn_readfirstlane(m1.x);
    int s2 = __builtin_amdgcn_readfirstlane(m2.x);
    int s3 = __builtin_amdgcn_readfirstlane(m3.x);
    float n0 = __builtin_bit_cast(float, __builtin_amdgcn_readfirstlane(m0.y));
    float n1 = __builtin_bit_cast(float, __builtin_amdgcn_readfirstlane(m1.y));
    float n2 = __builtin_bit_cast(float, __builtin_amdgcn_readfirstlane(m2.y));
    float n3 = __builtin_bit_cast(float, __builtin_amdgcn_readfirstlane(m3.y));
    unsigned int h0 = hu[(size_t)s0 * 64 + lane];
    unsigned int h1 = hu[(size_t)s1 * 64 + lane];
    unsigned int h2 = hu[(size_t)s2 * 64 + lane];
    unsigned int h3 = hu[(size_t)s3 * 64 + lane];
    acc0 += bflo(h0) * n0 + bflo(h1) * n1 + bflo(h2) * n2 + bflo(h3) * n3;
    acc1 += bfhi(h0) * n0 + bfhi(h1) * n1 + bfhi(h2) * n2 + bfhi(h3) * n3;
  }
  for (; e < end; ++e) {
    uint2 m0 = eadj[e];
    int s0 = __builtin_amdgcn_readfirstlane(m0.x);
    float n0 = __builtin_bit_cast(float, __builtin_amdgcn_readfirstlane(m0.y));
    unsigned int h0 = hu[(size_t)s0 * 64 + lane];
    acc0 += bflo(h0) * n0;
    acc1 += bfhi(h0) * n0;
  }
  float2 b = reinterpret_cast<const float2*>(bias)[lane];
  float r0 = fmaxf(acc0 + b.x, 0.f);
  float r1 = fmaxf(acc1 + b.y, 0.f);
  o1b[(size_t)node * 64 + lane] = packbf(r0, r1);
}

// ---------------- fused layer-2 aggregation + layer-3 GEMV ----------------
// o2 = b2 + h2[n]*dinv^2 + sum h2[src]*nrm ; h3[n] = sum_d relu(o2)[d] * W3[d]
__global__ void agg_l23_k(const int* __restrict__ row, const uint2* __restrict__ eadj,
                          const unsigned short* __restrict__ h2, const float* __restrict__ b2,
                          const float* __restrict__ W3, const float* __restrict__ dinv,
                          float* __restrict__ h3, int N) {
  const int lane = threadIdx.x & 63;
  const int half = lane >> 5;
  const int l = lane & 31;
  const int node = blockIdx.x * (blockDim.x >> 6) + (threadIdx.x >> 6);
  if (node >= N) return;
  const unsigned int* hu = reinterpret_cast<const unsigned int*>(h2);  // [N][32] pairs
  const int beg = row[node], end = row[node + 1];
  float acc0 = 0.f, acc1 = 0.f;
  {
    const float di = dinv[node];
    unsigned int hv = hu[(size_t)node * 32 + l];
    float di2 = (half == 0) ? di * di : 0.f;
    acc0 = bflo(hv) * di2;
    acc1 = bfhi(hv) * di2;
  }
  int e = beg + half;
  for (; e + 2 < end; e += 4) {  // this half handles e, e+2
    uint2 ma = eadj[e], mb = eadj[e + 2];
    float na = __builtin_bit_cast(float, ma.y);
    float nb = __builtin_bit_cast(float, mb.y);
    unsigned int ha = hu[(size_t)ma.x * 32 + l];
    unsigned int hb = hu[(size_t)mb.x * 32 + l];
    acc0 += bflo(ha) * na + bflo(hb) * nb;
    acc1 += bfhi(ha) * na + bfhi(hb) * nb;
  }
  if (e < end) {
    uint2 ma = eadj[e];
    float na = __builtin_bit_cast(float, ma.y);
    unsigned int ha = hu[(size_t)ma.x * 32 + l];
    acc0 += bflo(ha) * na;
    acc1 += bfhi(ha) * na;
  }
  acc0 += __shfl_xor(acc0, 32, 64);
  acc1 += __shfl_xor(acc1, 32, 64);
  float2 bb = reinterpret_cast<const float2*>(b2)[l];
  float2 w3 = reinterpret_cast<const float2*>(W3)[l];
  float v = fmaxf(acc0 + bb.x, 0.f) * w3.x + fmaxf(acc1 + bb.y, 0.f) * w3.y;
#pragma unroll
  for (int off = 16; off > 0; off >>= 1) v += __shfl_xor(v, off, 64);
  if (lane == 0) h3[node] = v;  // both halves computed identical sums; lane0 writes
}

// ---------------- layer-3 aggregation: thread per node ----------------
__global__ void agg_csr1_k(const int* __restrict__ row, const uint2* __restrict__ eadj,
                           const float* __restrict__ h3, const float* __restrict__ b3,
                           const float* __restrict__ dinv, float* __restrict__ out, int N) {
  int n = blockIdx.x * blockDim.x + threadIdx.x;
  if (n >= N) return;
  float di = dinv[n];
  float acc = h3[n] * di * di;
  const int beg = row[n], end = row[n + 1];
  int e = beg;
  for (; e + 2 <= end; e += 2) {
    uint2 m0 = eadj[e], m1 = eadj[e + 1];
    acc += h3[m0.x] * __builtin_bit_cast(float, m0.y)
         + h3[m1.x] * __builtin_bit_cast(float, m1.y);
  }
  if (e < end) {
    uint2 m = eadj[e];
    acc += h3[m.x] * __builtin_bit_cast(float, m.y);
  }
  out[n] = acc + b3[0];
}

// ---------------- launch ----------------
extern "C" void kernel_launch(void* const* d_in, const int* in_sizes, int n_in,
                              void* d_out, int out_size, void* d_ws, size_t ws_size,
                              hipStream_t stream) {
  const float* x  = (const float*)d_in[0];
  const int*   ei = (const int*)d_in[1];
  const float* ea = (const float*)d_in[2];
  const float* W1 = (const float*)d_in[3];
  const float* b1 = (const float*)d_in[4];
  const float* W2 = (const float*)d_in[5];
  const float* b2 = (const float*)d_in[6];
  const float* W3 = (const float*)d_in[7];
  const float* b3 = (const float*)d_in[8];
  float* out = (float*)d_out;

  const int N = in_sizes[0] / 512;  // 100000
  const int E = in_sizes[2];        // 1600000
  const int* src = ei;
  const int* dst = ei + E;

  char* w = (char*)d_ws;
  auto alloc = [&](size_t bytes) {
    char* p = w; w += (bytes + 511) & ~(size_t)511; return p;
  };
  float* dinv         = (float*)alloc((size_t)N * 4);
  int*   cnt          = (int*)alloc((size_t)N * 4);
  int*   rowp         = (int*)alloc((size_t)(N + 1) * 4);
  int*   bsum         = (int*)alloc(4096 * 4);
  int*   rank         = (int*)alloc((size_t)E * 4);
  uint2* eadj         = (uint2*)alloc((size_t)E * 8);
  unsigned short* h1  = (unsigned short*)alloc((size_t)N * 128 * 2);
  unsigned int* o1b   = (unsigned int*)alloc((size_t)N * 64 * 4);   // relu(o1+b1) bf16x2
  unsigned short* h2  = (unsigned short*)alloc((size_t)N * 64 * 2);
  float* h3           = (float*)alloc((size_t)N * 4);
  unsigned short* wt1 = (unsigned short*)alloc(512 * 128 * 2);
  unsigned short* wt2 = (unsigned short*)alloc(128 * 64 * 2);

  const int TB = 256;
  const int nb_scan = (N + 2047) / 2048;

  hipMemsetAsync(cnt, 0, (size_t)N * 4, stream);

  // CSR build: hist(+rank) -> scan -> scatter (atomic-free) -> deg/dinv -> norms
  hist_rank_k<<<(E + TB - 1) / TB, TB, 0, stream>>>(dst, cnt, rank, E);
  scan1_k<<<nb_scan, 256, 0, stream>>>(cnt, rowp, bsum, N);
  scan2_k<<<1, 64, 0, stream>>>(bsum, nb_scan);
  scan3_k<<<(N + 1 + TB - 1) / TB, TB, 0, stream>>>(rowp, bsum, N, E);
  scatter_nr_k<<<(E + TB - 1) / TB, TB, 0, stream>>>(src, dst, ea, rowp, rank, eadj, E);
  deg_dinv_k<<<(N + TB - 1) / TB, TB, 0, stream>>>(rowp, eadj, dinv, N);
  fixnorm_k<<<(N + TB - 1) / TB, TB, 0, stream>>>(rowp, eadj, dinv, N);
  conv_wt2_k<<<(512 * 128 + 128 * 64 + TB - 1) / TB, TB, 0, stream>>>(W1, wt1, W2, wt2);

  const int gblocks = (N + 127) / 128;
  const int ablocks = (N + 3) / 4;
  // layer 1
  gemm_f32a_k<128, 512><<<gblocks, TB, 0, stream>>>(x, wt1, h1, N);
  agg_csr128_k<<<ablocks, TB, 0, stream>>>(rowp, eadj, h1, b1, dinv, o1b, N);
  // layer 2 (A already relu'd bf16)
  gemm_bf16a_k<<<gblocks, TB, 0, stream>>>((const unsigned short*)o1b, wt2, h2, N);
  // fused layer-2 agg + layer-3 gemv
  agg_l23_k<<<ablocks, TB, 0, stream>>>(rowp, eadj, h2, b2, W3, dinv, h3, N);
  // layer 3 aggregation
  agg_csr1_k<<<(N + TB - 1) / TB, TB, 0, stream>>>(rowp, eadj, h3, b3, dinv, out, N);
}

// Round 5
// 640.050 us; speedup vs baseline: 2.4141x; 1.0322x over previous
//
#include <hip/hip_runtime.h>

typedef __attribute__((ext_vector_type(4))) float f32x4;
typedef __attribute__((ext_vector_type(8))) short bf16x8;
typedef __attribute__((ext_vector_type(4))) unsigned short u16x4;

__device__ __forceinline__ unsigned short f2bf(float f) {
  unsigned int u = __builtin_bit_cast(unsigned int, f);
  u += 0x7fffu + ((u >> 16) & 1u);   // round-to-nearest-even
  return (unsigned short)(u >> 16);
}
__device__ __forceinline__ float bf2f(unsigned short h) {
  unsigned int u = ((unsigned int)h) << 16;
  return __builtin_bit_cast(float, u);
}
__device__ __forceinline__ float bflo(unsigned int u) { return bf2f((unsigned short)(u & 0xffffu)); }
__device__ __forceinline__ float bfhi(unsigned int u) { return bf2f((unsigned short)(u >> 16)); }
__device__ __forceinline__ unsigned int packbf(float a, float b) {
  return (unsigned int)f2bf(a) | ((unsigned int)f2bf(b) << 16);
}

// ---------------- CSR build ----------------
// one atomic per edge: returned old count == within-bucket rank
__global__ void hist_rank_k(const int* __restrict__ dst, int* __restrict__ cnt,
                            int* __restrict__ rank, int E) {
  int e = blockIdx.x * blockDim.x + threadIdx.x;
  if (e < E) rank[e] = atomicAdd(&cnt[dst[e]], 1);
}

__global__ void scan1_k(const int* __restrict__ cnt, int* __restrict__ row,
                        int* __restrict__ bsum, int N) {
  __shared__ int sh[256];
  const int tid = threadIdx.x;
  const int base = blockIdx.x * 2048 + tid * 8;
  int v[8]; int s = 0;
#pragma unroll
  for (int i = 0; i < 8; ++i) {
    int idx = base + i;
    v[i] = (idx < N) ? cnt[idx] : 0;
    s += v[i];
  }
  sh[tid] = s;
  __syncthreads();
  for (int off = 1; off < 256; off <<= 1) {
    int t = (tid >= off) ? sh[tid - off] : 0;
    __syncthreads();
    sh[tid] += t;
    __syncthreads();
  }
  int excl = sh[tid] - s;
  if (tid == 255) bsum[blockIdx.x] = sh[255];
  int run = excl;
#pragma unroll
  for (int i = 0; i < 8; ++i) {
    int idx = base + i;
    if (idx < N) row[idx] = run;
    run += v[i];
  }
}
// merged scan2+scan3: each block serially prefixes <=49 block sums (L2-hot)
__global__ void scan23_k(int* __restrict__ row, const int* __restrict__ bsum, int N, int E) {
  __shared__ int pref;
  const int seg = (int)((blockIdx.x * blockDim.x) >> 11);  // constant within block (256 | 2048)
  if (threadIdx.x == 0) {
    int s = 0;
    for (int i = 0; i < seg; ++i) s += bsum[i];
    pref = s;
  }
  __syncthreads();
  int idx = blockIdx.x * blockDim.x + threadIdx.x;
  if (idx < N) row[idx] += pref;
  if (idx == N) row[N] = E;
}
// atomic-free scatter: pos = row[dst] + rank. Stores (src, raw ew).
__global__ void scatter_nr_k(const int* __restrict__ src, const int* __restrict__ dst,
                             const float* __restrict__ ew, const int* __restrict__ row,
                             const int* __restrict__ rank, uint2* __restrict__ eadj, int E) {
  int e = blockIdx.x * blockDim.x + threadIdx.x;
  if (e >= E) return;
  int pos = row[dst[e]] + rank[e];
  eadj[pos] = make_uint2((unsigned)src[e], __builtin_bit_cast(unsigned, ew[e]));
}
// weighted in-degree from sorted CSR (no atomics), dinv = rsqrt(1 + sum ew)
__global__ void deg_dinv_k(const int* __restrict__ row, const uint2* __restrict__ eadj,
                           float* __restrict__ dinv, int N) {
  int n = blockIdx.x * blockDim.x + threadIdx.x;
  if (n >= N) return;
  float s = 1.0f;  // self-loop weight
  int end = row[n + 1];
  for (int e = row[n]; e < end; ++e) s += __builtin_bit_cast(float, eadj[e].y);
  dinv[n] = rsqrtf(s);
}
// both weight matrices -> bf16 transposed, one launch
__global__ void conv_wt2_k(const float* __restrict__ W1, unsigned short* __restrict__ Wt1,
                           const float* __restrict__ W2, unsigned short* __restrict__ Wt2) {
  int idx = blockIdx.x * blockDim.x + threadIdx.x;
  if (idx < 512 * 128) {
    int n = idx >> 9, k = idx & 511;               // Wt1[n][k] = W1[k][n]
    Wt1[idx] = f2bf(W1[k * 128 + n]);
  } else {
    int j = idx - 512 * 128;
    if (j < 128 * 64) {
      int n = j >> 7, k = j & 127;                 // Wt2[n][k] = W2[k][n]
      Wt2[j] = f2bf(W2[k * 64 + n]);
    }
  }
}

// ---------------- layer-1 GEMM: A fp32, bf16 MFMA, writes h1 bf16 ----------------
template<int NC, int KD>
__launch_bounds__(256, 2)
__global__ void gemm_f32a_k(const float* __restrict__ A, const unsigned short* __restrict__ Wt,
                            unsigned short* __restrict__ Hb, int M) {
  constexpr int BM = 128, BK = 64;
  constexpr int WN = 64;
  constexpr int WGN = NC / WN;
  constexpr int WGM = 4 / WGN;
  constexpr int WM = BM / WGM;
  constexpr int FM = WM / 16;
  constexpr int FN = WN / 16;
  constexpr int KSUB = BK / 32;
  constexpr int A_PER_T = BM * (BK / 4) / 256;
  constexpr int B_PER_T = NC * (BK / 8) / 256;
  constexpr int nT = KD / BK;

  __shared__ unsigned short As[BM * BK];
  __shared__ unsigned short Bs[NC * BK];
  char* asb = reinterpret_cast<char*>(As);
  char* bsb = reinterpret_cast<char*>(Bs);

  const int tid = threadIdx.x;
  const int lane = tid & 63;
  const int wid = tid >> 6;
  const int wr = wid / WGN;
  const int wc = wid % WGN;
  const int lg = lane >> 4;
  const int lr = lane & 15;
  const int blockM = blockIdx.x * BM;

  float4 areg[A_PER_T];
  uint4 breg[B_PER_T];

  auto load_tiles = [&](int k0) {
#pragma unroll
    for (int i = 0; i < A_PER_T; ++i) {
      int chunk = tid + i * 256;
      int r = chunk >> 4, c4 = chunk & 15;
      int gr = blockM + r; if (gr >= M) gr = M - 1;
      areg[i] = *reinterpret_cast<const float4*>(A + (size_t)gr * KD + k0 + c4 * 4);
    }
#pragma unroll
    for (int i = 0; i < B_PER_T; ++i) {
      int chunk = tid + i * 256;
      int n = chunk >> 3, c = chunk & 7;
      breg[i] = *reinterpret_cast<const uint4*>(Wt + (size_t)n * KD + k0 + c * 8);
    }
  };

  f32x4 acc[FM][FN] = {};
  load_tiles(0);

  for (int t = 0; t < nT; ++t) {
    __syncthreads();
#pragma unroll
    for (int i = 0; i < A_PER_T; ++i) {
      int chunk = tid + i * 256;
      int r = chunk >> 4, c4 = chunk & 15;
      float4 v = areg[i];
      u16x4 p = { f2bf(v.x), f2bf(v.y), f2bf(v.z), f2bf(v.w) };
      int byte = r * (BK * 2) + ((c4 * 8) ^ ((r & 7) << 4));
      *reinterpret_cast<u16x4*>(asb + byte) = p;
    }
#pragma unroll
    for (int i = 0; i < B_PER_T; ++i) {
      int chunk = tid + i * 256;
      int n = chunk >> 3, c = chunk & 7;
      int byte = n * (BK * 2) + ((c * 16) ^ ((n & 7) << 4));
      *reinterpret_cast<uint4*>(bsb + byte) = breg[i];
    }
    __syncthreads();
    if (t + 1 < nT) load_tiles((t + 1) * BK);

    bf16x8 af[FM][KSUB], bfr[FN][KSUB];
#pragma unroll
    for (int fm = 0; fm < FM; ++fm)
#pragma unroll
      for (int kk = 0; kk < KSUB; ++kk) {
        int row = wr * WM + fm * 16 + lr;
        int k = kk * 32 + lg * 8;
        int byte = row * (BK * 2) + ((k * 2) ^ ((row & 7) << 4));
        af[fm][kk] = *reinterpret_cast<const bf16x8*>(asb + byte);
      }
#pragma unroll
    for (int fn = 0; fn < FN; ++fn)
#pragma unroll
      for (int kk = 0; kk < KSUB; ++kk) {
        int n = wc * WN + fn * 16 + lr;
        int k = kk * 32 + lg * 8;
        int byte = n * (BK * 2) + ((k * 2) ^ ((n & 7) << 4));
        bfr[fn][kk] = *reinterpret_cast<const bf16x8*>(bsb + byte);
      }
#pragma unroll
    for (int kk = 0; kk < KSUB; ++kk)
#pragma unroll
      for (int fm = 0; fm < FM; ++fm)
#pragma unroll
        for (int fn = 0; fn < FN; ++fn)
          acc[fm][fn] = __builtin_amdgcn_mfma_f32_16x16x32_bf16(
              af[fm][kk], bfr[fn][kk], acc[fm][fn], 0, 0, 0);
  }

#pragma unroll
  for (int fm = 0; fm < FM; ++fm)
#pragma unroll
    for (int fn = 0; fn < FN; ++fn) {
      int col = wc * WN + fn * 16 + lr;
#pragma unroll
      for (int j = 0; j < 4; ++j) {
        int row = blockM + wr * WM + fm * 16 + lg * 4 + j;
        if (row < M)
          Hb[(size_t)row * NC + col] = f2bf(acc[fm][fn][j]);
      }
    }
}

// ---------------- layer-2 GEMM: A bf16 (already relu'd), writes h2 bf16 ----------------
__launch_bounds__(256, 2)
__global__ void gemm_bf16a_k(const unsigned short* __restrict__ A,  // [M][128] bf16
                             const unsigned short* __restrict__ Wt, // [64][128] bf16
                             unsigned short* __restrict__ Hb, int M) {
  constexpr int BM = 128, BK = 64, NC = 64, KD = 128;
  constexpr int WM = 32;        // 4 waves along M
  constexpr int FM = 2, FN = 4, KSUB = 2;
  constexpr int A_PER_T = 4;
  constexpr int B_PER_T = 2;
  constexpr int nT = KD / BK;   // 2

  __shared__ unsigned short As[BM * BK];
  __shared__ unsigned short Bs[NC * BK];
  char* asb = reinterpret_cast<char*>(As);
  char* bsb = reinterpret_cast<char*>(Bs);

  const int tid = threadIdx.x;
  const int lane = tid & 63;
  const int wid = tid >> 6;
  const int lg = lane >> 4;
  const int lr = lane & 15;
  const int blockM = blockIdx.x * BM;

  uint4 areg[A_PER_T];
  uint4 breg[B_PER_T];

  auto load_tiles = [&](int k0) {
#pragma unroll
    for (int i = 0; i < A_PER_T; ++i) {
      int chunk = tid + i * 256;
      int r = chunk >> 3, c = chunk & 7;
      int gr = blockM + r; if (gr >= M) gr = M - 1;
      areg[i] = *reinterpret_cast<const uint4*>(A + (size_t)gr * KD + k0 + c * 8);
    }
#pragma unroll
    for (int i = 0; i < B_PER_T; ++i) {
      int chunk = tid + i * 256;
      int n = chunk >> 3, c = chunk & 7;
      breg[i] = *reinterpret_cast<const uint4*>(Wt + (size_t)n * KD + k0 + c * 8);
    }
  };

  f32x4 acc[FM][FN] = {};
  load_tiles(0);

  for (int t = 0; t < nT; ++t) {
    __syncthreads();
#pragma unroll
    for (int i = 0; i < A_PER_T; ++i) {
      int chunk = tid + i * 256;
      int r = chunk >> 3, c = chunk & 7;
      int byte = r * (BK * 2) + ((c * 16) ^ ((r & 7) << 4));
      *reinterpret_cast<uint4*>(asb + byte) = areg[i];
    }
#pragma unroll
    for (int i = 0; i < B_PER_T; ++i) {
      int chunk = tid + i * 256;
      int n = chunk >> 3, c = chunk & 7;
      int byte = n * (BK * 2) + ((c * 16) ^ ((n & 7) << 4));
      *reinterpret_cast<uint4*>(bsb + byte) = breg[i];
    }
    __syncthreads();
    if (t + 1 < nT) load_tiles((t + 1) * BK);

    bf16x8 af[FM][KSUB], bfr[FN][KSUB];
#pragma unroll
    for (int fm = 0; fm < FM; ++fm)
#pragma unroll
      for (int kk = 0; kk < KSUB; ++kk) {
        int row = wid * WM + fm * 16 + lr;
        int k = kk * 32 + lg * 8;
        int byte = row * (BK * 2) + ((k * 2) ^ ((row & 7) << 4));
        af[fm][kk] = *reinterpret_cast<const bf16x8*>(asb + byte);
      }
#pragma unroll
    for (int fn = 0; fn < FN; ++fn)
#pragma unroll
      for (int kk = 0; kk < KSUB; ++kk) {
        int n = fn * 16 + lr;
        int k = kk * 32 + lg * 8;
        int byte = n * (BK * 2) + ((k * 2) ^ ((n & 7) << 4));
        bfr[fn][kk] = *reinterpret_cast<const bf16x8*>(bsb + byte);
      }
#pragma unroll
    for (int kk = 0; kk < KSUB; ++kk)
#pragma unroll
      for (int fm = 0; fm < FM; ++fm)
#pragma unroll
        for (int fn = 0; fn < FN; ++fn)
          acc[fm][fn] = __builtin_amdgcn_mfma_f32_16x16x32_bf16(
              af[fm][kk], bfr[fn][kk], acc[fm][fn], 0, 0, 0);
  }

#pragma unroll
  for (int fm = 0; fm < FM; ++fm)
#pragma unroll
    for (int fn = 0; fn < FN; ++fn) {
      int col = fn * 16 + lr;
#pragma unroll
      for (int j = 0; j < 4; ++j) {
        int row = blockM + wid * WM + fm * 16 + lg * 4 + j;
        if (row < M)
          Hb[(size_t)row * NC + col] = f2bf(acc[fm][fn][j]);
      }
    }
}

// ---------------- layer-1 aggregation: wave per node; on-the-fly norm; writes relu(o1+b1) bf16 ----------------
__global__ void agg_csr128_k(const int* __restrict__ row, const uint2* __restrict__ eadj,
                             const unsigned short* __restrict__ h, const float* __restrict__ bias,
                             const float* __restrict__ dinv, unsigned int* __restrict__ o1b, int N) {
  const int lane = threadIdx.x & 63;
  const int node = blockIdx.x * (blockDim.x >> 6) + (threadIdx.x >> 6);
  if (node >= N) return;
  const unsigned int* hu = reinterpret_cast<const unsigned int*>(h);  // [N][64] pairs
  const int beg = row[node], end = row[node + 1];
  const float di = dinv[node];
  const float di2 = di * di;
  unsigned int hv = hu[(size_t)node * 64 + lane];
  float acc0 = bflo(hv) * di2;
  float acc1 = bfhi(hv) * di2;
  int e = beg;
  for (; e + 8 <= end; e += 8) {
    uint2 m[8]; float dv[8]; unsigned int hh[8];
#pragma unroll
    for (int i = 0; i < 8; ++i) m[i] = eadj[e + i];
#pragma unroll
    for (int i = 0; i < 8; ++i) dv[i] = dinv[m[i].x];
#pragma unroll
    for (int i = 0; i < 8; ++i) hh[i] = hu[(size_t)m[i].x * 64 + lane];
#pragma unroll
    for (int i = 0; i < 8; ++i) {
      float nm = __builtin_bit_cast(float, m[i].y) * dv[i] * di;
      acc0 += bflo(hh[i]) * nm;
      acc1 += bfhi(hh[i]) * nm;
    }
  }
  for (; e < end; ++e) {
    uint2 m = eadj[e];
    float nm = __builtin_bit_cast(float, m.y) * dinv[m.x] * di;
    unsigned int h0 = hu[(size_t)m.x * 64 + lane];
    acc0 += bflo(h0) * nm;
    acc1 += bfhi(h0) * nm;
  }
  float2 b = reinterpret_cast<const float2*>(bias)[lane];
  float r0 = fmaxf(acc0 + b.x, 0.f);
  float r1 = fmaxf(acc1 + b.y, 0.f);
  o1b[(size_t)node * 64 + lane] = packbf(r0, r1);
}

// ---------------- fused layer-2 aggregation + layer-3 GEMV (on-the-fly norm) ----------------
__global__ void agg_l23_k(const int* __restrict__ row, const uint2* __restrict__ eadj,
                          const unsigned short* __restrict__ h2, const float* __restrict__ b2,
                          const float* __restrict__ W3, const float* __restrict__ dinv,
                          float* __restrict__ h3, int N) {
  const int lane = threadIdx.x & 63;
  const int half = lane >> 5;
  const int l = lane & 31;
  const int node = blockIdx.x * (blockDim.x >> 6) + (threadIdx.x >> 6);
  if (node >= N) return;
  const unsigned int* hu = reinterpret_cast<const unsigned int*>(h2);  // [N][32] pairs
  const int beg = row[node], end = row[node + 1];
  const float di = dinv[node];
  float acc0, acc1;
  {
    unsigned int hv = hu[(size_t)node * 32 + l];
    float di2 = (half == 0) ? di * di : 0.f;
    acc0 = bflo(hv) * di2;
    acc1 = bfhi(hv) * di2;
  }
  int e = beg + half;
  // this half handles edges e, e+2, e+4, e+6 (stride 2 interleave with other half)
  for (; e + 6 < end; e += 8) {
    uint2 m[4]; float dv[4]; unsigned int hh[4];
#pragma unroll
    for (int i = 0; i < 4; ++i) m[i] = eadj[e + 2 * i];
#pragma unroll
    for (int i = 0; i < 4; ++i) dv[i] = dinv[m[i].x];
#pragma unroll
    for (int i = 0; i < 4; ++i) hh[i] = hu[(size_t)m[i].x * 32 + l];
#pragma unroll
    for (int i = 0; i < 4; ++i) {
      float nm = __builtin_bit_cast(float, m[i].y) * dv[i] * di;
      acc0 += bflo(hh[i]) * nm;
      acc1 += bfhi(hh[i]) * nm;
    }
  }
  for (; e < end; e += 2) {
    uint2 m = eadj[e];
    float nm = __builtin_bit_cast(float, m.y) * dinv[m.x] * di;
    unsigned int hv = hu[(size_t)m.x * 32 + l];
    acc0 += bflo(hv) * nm;
    acc1 += bfhi(hv) * nm;
  }
  acc0 += __shfl_xor(acc0, 32, 64);
  acc1 += __shfl_xor(acc1, 32, 64);
  float2 bb = reinterpret_cast<const float2*>(b2)[l];
  float2 w3 = reinterpret_cast<const float2*>(W3)[l];
  float v = fmaxf(acc0 + bb.x, 0.f) * w3.x + fmaxf(acc1 + bb.y, 0.f) * w3.y;
#pragma unroll
  for (int off = 16; off > 0; off >>= 1) v += __shfl_xor(v, off, 64);
  if (lane == 0) h3[node] = v;
}

// ---------------- layer-3 aggregation: thread per node (on-the-fly norm) ----------------
__global__ void agg_csr1_k(const int* __restrict__ row, const uint2* __restrict__ eadj,
                           const float* __restrict__ h3, const float* __restrict__ b3,
                           const float* __restrict__ dinv, float* __restrict__ out, int N) {
  int n = blockIdx.x * blockDim.x + threadIdx.x;
  if (n >= N) return;
  float di = dinv[n];
  float acc = h3[n] * di * di;
  const int beg = row[n], end = row[n + 1];
  int e = beg;
  for (; e + 4 <= end; e += 4) {
    uint2 m[4]; float dv[4]; float hv[4];
#pragma unroll
    for (int i = 0; i < 4; ++i) m[i] = eadj[e + i];
#pragma unroll
    for (int i = 0; i < 4; ++i) dv[i] = dinv[m[i].x];
#pragma unroll
    for (int i = 0; i < 4; ++i) hv[i] = h3[m[i].x];
#pragma unroll
    for (int i = 0; i < 4; ++i)
      acc += hv[i] * (__builtin_bit_cast(float, m[i].y) * dv[i] * di);
  }
  for (; e < end; ++e) {
    uint2 m = eadj[e];
    float nm = __builtin_bit_cast(float, m.y) * dinv[m.x] * di;
    acc += h3[m.x] * nm;
  }
  out[n] = acc + b3[0];
}

// ---------------- launch ----------------
extern "C" void kernel_launch(void* const* d_in, const int* in_sizes, int n_in,
                              void* d_out, int out_size, void* d_ws, size_t ws_size,
                              hipStream_t stream) {
  const float* x  = (const float*)d_in[0];
  const int*   ei = (const int*)d_in[1];
  const float* ea = (const float*)d_in[2];
  const float* W1 = (const float*)d_in[3];
  const float* b1 = (const float*)d_in[4];
  const float* W2 = (const float*)d_in[5];
  const float* b2 = (const float*)d_in[6];
  const float* W3 = (const float*)d_in[7];
  const float* b3 = (const float*)d_in[8];
  float* out = (float*)d_out;

  const int N = in_sizes[0] / 512;  // 100000
  const int E = in_sizes[2];        // 1600000
  const int* src = ei;
  const int* dst = ei + E;

  char* w = (char*)d_ws;
  auto alloc = [&](size_t bytes) {
    char* p = w; w += (bytes + 511) & ~(size_t)511; return p;
  };
  float* dinv         = (float*)alloc((size_t)N * 4);
  int*   cnt          = (int*)alloc((size_t)N * 4);
  int*   rowp         = (int*)alloc((size_t)(N + 1) * 4);
  int*   bsum         = (int*)alloc(4096 * 4);
  int*   rank         = (int*)alloc((size_t)E * 4);
  uint2* eadj         = (uint2*)alloc((size_t)E * 8);
  unsigned short* h1  = (unsigned short*)alloc((size_t)N * 128 * 2);
  unsigned int* o1b   = (unsigned int*)alloc((size_t)N * 64 * 4);   // relu(o1+b1) bf16x2
  unsigned short* h2  = (unsigned short*)alloc((size_t)N * 64 * 2);
  float* h3           = (float*)alloc((size_t)N * 4);
  unsigned short* wt1 = (unsigned short*)alloc(512 * 128 * 2);
  unsigned short* wt2 = (unsigned short*)alloc(128 * 64 * 2);

  const int TB = 256;
  const int nb_scan = (N + 2047) / 2048;

  hipMemsetAsync(cnt, 0, (size_t)N * 4, stream);

  // CSR build: hist(+rank) -> scan -> scatter (atomic-free) -> deg/dinv
  hist_rank_k<<<(E + TB - 1) / TB, TB, 0, stream>>>(dst, cnt, rank, E);
  scan1_k<<<nb_scan, 256, 0, stream>>>(cnt, rowp, bsum, N);
  scan23_k<<<(N + 1 + TB - 1) / TB, TB, 0, stream>>>(rowp, bsum, N, E);
  scatter_nr_k<<<(E + TB - 1) / TB, TB, 0, stream>>>(src, dst, ea, rowp, rank, eadj, E);
  deg_dinv_k<<<(N + TB - 1) / TB, TB, 0, stream>>>(rowp, eadj, dinv, N);
  conv_wt2_k<<<(512 * 128 + 128 * 64 + TB - 1) / TB, TB, 0, stream>>>(W1, wt1, W2, wt2);

  const int gblocks = (N + 127) / 128;
  const int ablocks = (N + 3) / 4;
  // layer 1
  gemm_f32a_k<128, 512><<<gblocks, TB, 0, stream>>>(x, wt1, h1, N);
  agg_csr128_k<<<ablocks, TB, 0, stream>>>(rowp, eadj, h1, b1, dinv, o1b, N);
  // layer 2 (A already relu'd bf16)
  gemm_bf16a_k<<<gblocks, TB, 0, stream>>>((const unsigned short*)o1b, wt2, h2, N);
  // fused layer-2 agg + layer-3 gemv
  agg_l23_k<<<ablocks, TB, 0, stream>>>(rowp, eadj, h2, b2, W3, dinv, h3, N);
  // layer 3 aggregation
  agg_csr1_k<<<(N + TB - 1) / TB, TB, 0, stream>>>(rowp, eadj, h3, b3, dinv, out, N);
}

// Round 6
// 599.143 us; speedup vs baseline: 2.5790x; 1.0683x over previous
//
#include <hip/hip_runtime.h>

typedef __attribute__((ext_vector_type(4))) float f32x4;
typedef __attribute__((ext_vector_type(8))) short bf16x8;
typedef __attribute__((ext_vector_type(4))) unsigned short u16x4;

__device__ __forceinline__ unsigned short f2bf(float f) {
  unsigned int u = __builtin_bit_cast(unsigned int, f);
  u += 0x7fffu + ((u >> 16) & 1u);   // round-to-nearest-even
  return (unsigned short)(u >> 16);
}
__device__ __forceinline__ float bf2f(unsigned short h) {
  unsigned int u = ((unsigned int)h) << 16;
  return __builtin_bit_cast(float, u);
}
__device__ __forceinline__ float bflo(unsigned int u) { return bf2f((unsigned short)(u & 0xffffu)); }
__device__ __forceinline__ float bfhi(unsigned int u) { return bf2f((unsigned short)(u >> 16)); }
__device__ __forceinline__ unsigned int packbf(float a, float b) {
  return (unsigned int)f2bf(a) | ((unsigned int)f2bf(b) << 16);
}

// ======================= bucket-partition CSR build =======================
// Buckets of 128 nodes; nbkt = ceil(N/128) <= 1024. Edge payload packed as
// (src | (dst&127)<<17, ew) -- src < 2^17.
#define CHUNK 8192

// A1: global bucket counts via LDS histogram (~nbkt atomics per block)
__global__ void bkt_count_k(const int* __restrict__ dst, int* __restrict__ gcount,
                            int E, int nbkt) {
  __shared__ int hist[1024];
  for (int i = threadIdx.x; i < nbkt; i += 256) hist[i] = 0;
  __syncthreads();
  const int base = blockIdx.x * CHUNK;
  const int cend = min(base + CHUNK, E);
  for (int e = base + threadIdx.x; e < cend; e += 256)
    atomicAdd(&hist[dst[e] >> 7], 1);
  __syncthreads();
  for (int b = threadIdx.x; b < nbkt; b += 256)
    if (hist[b]) atomicAdd(&gcount[b], hist[b]);
}

// A2: exclusive scan of bucket counts -> gbase; init gcursor = gbase
__global__ void bkt_scan_k(const int* __restrict__ gcount, int* __restrict__ gbase,
                           int* __restrict__ gcursor, int nbkt) {
  __shared__ int sh[256];
  const int tid = threadIdx.x;
  int v[4]; int s = 0;
#pragma unroll
  for (int i = 0; i < 4; ++i) {
    int idx = tid * 4 + i;
    v[i] = (idx < nbkt) ? gcount[idx] : 0;
    s += v[i];
  }
  sh[tid] = s;
  __syncthreads();
  for (int off = 1; off < 256; off <<= 1) {
    int t = (tid >= off) ? sh[tid - off] : 0;
    __syncthreads();
    sh[tid] += t;
    __syncthreads();
  }
  int run = sh[tid] - s;
#pragma unroll
  for (int i = 0; i < 4; ++i) {
    int idx = tid * 4 + i;
    if (idx < nbkt) { gbase[idx] = run; gcursor[idx] = run; }
    run += v[i];
  }
}

// A3: partition edges into bucket regions (one global atomic per block-bucket run)
__global__ void bkt_part_k(const int* __restrict__ src, const int* __restrict__ dst,
                           const float* __restrict__ ew, int* __restrict__ gcursor,
                           uint2* __restrict__ part, int E, int nbkt) {
  __shared__ int hist[1024];
  __shared__ int rbase[1024];
  for (int i = threadIdx.x; i < nbkt; i += 256) hist[i] = 0;
  __syncthreads();
  const int cbase = blockIdx.x * CHUNK;
  const int cend = min(cbase + CHUNK, E);
  for (int e = cbase + threadIdx.x; e < cend; e += 256)
    atomicAdd(&hist[dst[e] >> 7], 1);
  __syncthreads();
  for (int b = threadIdx.x; b < nbkt; b += 256) {
    int h = hist[b];
    rbase[b] = h ? atomicAdd(&gcursor[b], h) : 0;
    hist[b] = 0;  // reuse as local cursor
  }
  __syncthreads();
  for (int e = cbase + threadIdx.x; e < cend; e += 256) {
    int d = dst[e];
    int b = d >> 7;
    int r = atomicAdd(&hist[b], 1);
    unsigned packed = (unsigned)src[e] | ((unsigned)(d & 127) << 17);
    part[rbase[b] + r] = make_uint2(packed, __builtin_bit_cast(unsigned, ew[e]));
  }
}

// B: per-bucket counting sort in LDS -> eadj, rowp, dinv (fused weighted degree)
#define MAXE_BKT 4096
__global__ void bkt_build_k(const int* __restrict__ gbase, const uint2* __restrict__ part,
                            int* __restrict__ rowp, float* __restrict__ dinv,
                            uint2* __restrict__ eadj, int N, int E, int nbkt) {
  __shared__ uint2 stage[MAXE_BKT];
  __shared__ int hist[128];
  __shared__ float degs[128];
  __shared__ int lbase[128];
  const int bkt = blockIdx.x;
  const int tid = threadIdx.x;
  const int ebeg = gbase[bkt];
  const int eend = (bkt + 1 < nbkt) ? gbase[bkt + 1] : E;
  int ne = eend - ebeg;
  if (ne > MAXE_BKT) ne = MAXE_BKT;   // impossible for this input (mean 2048, +45 sigma)
  const int node0 = bkt << 7;
  const int nn = min(128, N - node0);
  if (tid < 128) { hist[tid] = 0; degs[tid] = 1.0f; }  // self-loop weight
  __syncthreads();
  for (int i = tid; i < ne; i += 256) {
    uint2 m = part[ebeg + i];
    stage[i] = m;
    int bin = (m.x >> 17) & 127;
    atomicAdd(&hist[bin], 1);
    atomicAdd(&degs[bin], __builtin_bit_cast(float, m.y));
  }
  __syncthreads();
  // exclusive scan of hist[0..127] using one wave (2 elems/lane)
  if (tid < 64) {
    int a = hist[2 * tid], b = hist[2 * tid + 1];
    int s = a + b;
    int run = s;
#pragma unroll
    for (int off = 1; off < 64; off <<= 1) {
      int t = __shfl_up(run, off, 64);
      if (tid >= off) run += t;
    }
    int excl = run - s;
    lbase[2 * tid] = excl;
    lbase[2 * tid + 1] = excl + a;
  }
  __syncthreads();
  if (tid < nn) {
    rowp[node0 + tid] = ebeg + lbase[tid];
    dinv[node0 + tid] = rsqrtf(degs[tid]);
  }
  if (bkt == 0 && tid == 0) rowp[N] = E;
  if (tid < 128) hist[tid] = 0;  // reuse as cursor
  __syncthreads();
  for (int i = tid; i < ne; i += 256) {
    uint2 m = stage[i];
    int bin = (m.x >> 17) & 127;
    int r = atomicAdd(&hist[bin], 1);
    eadj[ebeg + lbase[bin] + r] = make_uint2(m.x & 0x1FFFFu, m.y);
  }
}

// both weight matrices -> bf16 transposed, one launch
__global__ void conv_wt2_k(const float* __restrict__ W1, unsigned short* __restrict__ Wt1,
                           const float* __restrict__ W2, unsigned short* __restrict__ Wt2) {
  int idx = blockIdx.x * blockDim.x + threadIdx.x;
  if (idx < 512 * 128) {
    int n = idx >> 9, k = idx & 511;               // Wt1[n][k] = W1[k][n]
    Wt1[idx] = f2bf(W1[k * 128 + n]);
  } else {
    int j = idx - 512 * 128;
    if (j < 128 * 64) {
      int n = j >> 7, k = j & 127;                 // Wt2[n][k] = W2[k][n]
      Wt2[j] = f2bf(W2[k * 64 + n]);
    }
  }
}

// ============ layer-1 GEMM: A fp32, bf16 MFMA, writes h1' = h1*dinv (bf16) ============
template<int NC, int KD>
__launch_bounds__(256, 2)
__global__ void gemm_f32a_k(const float* __restrict__ A, const unsigned short* __restrict__ Wt,
                            const float* __restrict__ dinv, unsigned short* __restrict__ Hb,
                            int M) {
  constexpr int BM = 128, BK = 64;
  constexpr int WN = 64;
  constexpr int WGN = NC / WN;
  constexpr int WGM = 4 / WGN;
  constexpr int WM = BM / WGM;
  constexpr int FM = WM / 16;
  constexpr int FN = WN / 16;
  constexpr int KSUB = BK / 32;
  constexpr int A_PER_T = BM * (BK / 4) / 256;
  constexpr int B_PER_T = NC * (BK / 8) / 256;
  constexpr int nT = KD / BK;

  __shared__ unsigned short As[BM * BK];
  __shared__ unsigned short Bs[NC * BK];
  char* asb = reinterpret_cast<char*>(As);
  char* bsb = reinterpret_cast<char*>(Bs);

  const int tid = threadIdx.x;
  const int lane = tid & 63;
  const int wid = tid >> 6;
  const int wr = wid / WGN;
  const int wc = wid % WGN;
  const int lg = lane >> 4;
  const int lr = lane & 15;
  const int blockM = blockIdx.x * BM;

  float4 areg[A_PER_T];
  uint4 breg[B_PER_T];

  auto load_tiles = [&](int k0) {
#pragma unroll
    for (int i = 0; i < A_PER_T; ++i) {
      int chunk = tid + i * 256;
      int r = chunk >> 4, c4 = chunk & 15;
      int gr = blockM + r; if (gr >= M) gr = M - 1;
      areg[i] = *reinterpret_cast<const float4*>(A + (size_t)gr * KD + k0 + c4 * 4);
    }
#pragma unroll
    for (int i = 0; i < B_PER_T; ++i) {
      int chunk = tid + i * 256;
      int n = chunk >> 3, c = chunk & 7;
      breg[i] = *reinterpret_cast<const uint4*>(Wt + (size_t)n * KD + k0 + c * 8);
    }
  };

  f32x4 acc[FM][FN] = {};
  load_tiles(0);

  for (int t = 0; t < nT; ++t) {
    __syncthreads();
#pragma unroll
    for (int i = 0; i < A_PER_T; ++i) {
      int chunk = tid + i * 256;
      int r = chunk >> 4, c4 = chunk & 15;
      float4 v = areg[i];
      u16x4 p = { f2bf(v.x), f2bf(v.y), f2bf(v.z), f2bf(v.w) };
      int byte = r * (BK * 2) + ((c4 * 8) ^ ((r & 7) << 4));
      *reinterpret_cast<u16x4*>(asb + byte) = p;
    }
#pragma unroll
    for (int i = 0; i < B_PER_T; ++i) {
      int chunk = tid + i * 256;
      int n = chunk >> 3, c = chunk & 7;
      int byte = n * (BK * 2) + ((c * 16) ^ ((n & 7) << 4));
      *reinterpret_cast<uint4*>(bsb + byte) = breg[i];
    }
    __syncthreads();
    if (t + 1 < nT) load_tiles((t + 1) * BK);

    bf16x8 af[FM][KSUB], bfr[FN][KSUB];
#pragma unroll
    for (int fm = 0; fm < FM; ++fm)
#pragma unroll
      for (int kk = 0; kk < KSUB; ++kk) {
        int row = wr * WM + fm * 16 + lr;
        int k = kk * 32 + lg * 8;
        int byte = row * (BK * 2) + ((k * 2) ^ ((row & 7) << 4));
        af[fm][kk] = *reinterpret_cast<const bf16x8*>(asb + byte);
      }
#pragma unroll
    for (int fn = 0; fn < FN; ++fn)
#pragma unroll
      for (int kk = 0; kk < KSUB; ++kk) {
        int n = wc * WN + fn * 16 + lr;
        int k = kk * 32 + lg * 8;
        int byte = n * (BK * 2) + ((k * 2) ^ ((n & 7) << 4));
        bfr[fn][kk] = *reinterpret_cast<const bf16x8*>(bsb + byte);
      }
#pragma unroll
    for (int kk = 0; kk < KSUB; ++kk)
#pragma unroll
      for (int fm = 0; fm < FM; ++fm)
#pragma unroll
        for (int fn = 0; fn < FN; ++fn)
          acc[fm][fn] = __builtin_amdgcn_mfma_f32_16x16x32_bf16(
              af[fm][kk], bfr[fn][kk], acc[fm][fn], 0, 0, 0);
  }

#pragma unroll
  for (int fm = 0; fm < FM; ++fm)
#pragma unroll
    for (int j = 0; j < 4; ++j) {
      int row = blockM + wr * WM + fm * 16 + lg * 4 + j;
      if (row < M) {
        float di = dinv[row];
#pragma unroll
        for (int fn = 0; fn < FN; ++fn) {
          int col = wc * WN + fn * 16 + lr;
          Hb[(size_t)row * NC + col] = f2bf(acc[fm][fn][j] * di);
        }
      }
    }
}

// ============ layer-2 GEMM: A bf16 (already relu'd), writes h2' = h2*dinv (bf16) ============
__launch_bounds__(256, 2)
__global__ void gemm_bf16a_k(const unsigned short* __restrict__ A,  // [M][128] bf16
                             const unsigned short* __restrict__ Wt, // [64][128] bf16
                             const float* __restrict__ dinv,
                             unsigned short* __restrict__ Hb, int M) {
  constexpr int BM = 128, BK = 64, NC = 64, KD = 128;
  constexpr int WM = 32;
  constexpr int FM = 2, FN = 4, KSUB = 2;
  constexpr int A_PER_T = 4;
  constexpr int B_PER_T = 2;
  constexpr int nT = KD / BK;   // 2

  __shared__ unsigned short As[BM * BK];
  __shared__ unsigned short Bs[NC * BK];
  char* asb = reinterpret_cast<char*>(As);
  char* bsb = reinterpret_cast<char*>(Bs);

  const int tid = threadIdx.x;
  const int lane = tid & 63;
  const int wid = tid >> 6;
  const int lg = lane >> 4;
  const int lr = lane & 15;
  const int blockM = blockIdx.x * BM;

  uint4 areg[A_PER_T];
  uint4 breg[B_PER_T];

  auto load_tiles = [&](int k0) {
#pragma unroll
    for (int i = 0; i < A_PER_T; ++i) {
      int chunk = tid + i * 256;
      int r = chunk >> 3, c = chunk & 7;
      int gr = blockM + r; if (gr >= M) gr = M - 1;
      areg[i] = *reinterpret_cast<const uint4*>(A + (size_t)gr * KD + k0 + c * 8);
    }
#pragma unroll
    for (int i = 0; i < B_PER_T; ++i) {
      int chunk = tid + i * 256;
      int n = chunk >> 3, c = chunk & 7;
      breg[i] = *reinterpret_cast<const uint4*>(Wt + (size_t)n * KD + k0 + c * 8);
    }
  };

  f32x4 acc[FM][FN] = {};
  load_tiles(0);

  for (int t = 0; t < nT; ++t) {
    __syncthreads();
#pragma unroll
    for (int i = 0; i < A_PER_T; ++i) {
      int chunk = tid + i * 256;
      int r = chunk >> 3, c = chunk & 7;
      int byte = r * (BK * 2) + ((c * 16) ^ ((r & 7) << 4));
      *reinterpret_cast<uint4*>(asb + byte) = areg[i];
    }
#pragma unroll
    for (int i = 0; i < B_PER_T; ++i) {
      int chunk = tid + i * 256;
      int n = chunk >> 3, c = chunk & 7;
      int byte = n * (BK * 2) + ((c * 16) ^ ((n & 7) << 4));
      *reinterpret_cast<uint4*>(bsb + byte) = breg[i];
    }
    __syncthreads();
    if (t + 1 < nT) load_tiles((t + 1) * BK);

    bf16x8 af[FM][KSUB], bfr[FN][KSUB];
#pragma unroll
    for (int fm = 0; fm < FM; ++fm)
#pragma unroll
      for (int kk = 0; kk < KSUB; ++kk) {
        int row = wid * WM + fm * 16 + lr;
        int k = kk * 32 + lg * 8;
        int byte = row * (BK * 2) + ((k * 2) ^ ((row & 7) << 4));
        af[fm][kk] = *reinterpret_cast<const bf16x8*>(asb + byte);
      }
#pragma unroll
    for (int fn = 0; fn < FN; ++fn)
#pragma unroll
      for (int kk = 0; kk < KSUB; ++kk) {
        int n = fn * 16 + lr;
        int k = kk * 32 + lg * 8;
        int byte = n * (BK * 2) + ((k * 2) ^ ((n & 7) << 4));
        bfr[fn][kk] = *reinterpret_cast<const bf16x8*>(bsb + byte);
      }
#pragma unroll
    for (int kk = 0; kk < KSUB; ++kk)
#pragma unroll
      for (int fm = 0; fm < FM; ++fm)
#pragma unroll
        for (int fn = 0; fn < FN; ++fn)
          acc[fm][fn] = __builtin_amdgcn_mfma_f32_16x16x32_bf16(
              af[fm][kk], bfr[fn][kk], acc[fm][fn], 0, 0, 0);
  }

#pragma unroll
  for (int fm = 0; fm < FM; ++fm)
#pragma unroll
    for (int j = 0; j < 4; ++j) {
      int row = blockM + wid * WM + fm * 16 + lg * 4 + j;
      if (row < M) {
        float di = dinv[row];
#pragma unroll
        for (int fn = 0; fn < FN; ++fn) {
          int col = fn * 16 + lr;
          Hb[(size_t)row * NC + col] = f2bf(acc[fm][fn][j] * di);
        }
      }
    }
}

// ====== layer-1 aggregation: wave per node; h pre-scaled; writes relu(o1+b1) bf16 ======
__global__ void agg_csr128_k(const int* __restrict__ row, const uint2* __restrict__ eadj,
                             const unsigned short* __restrict__ h, const float* __restrict__ bias,
                             const float* __restrict__ dinv, unsigned int* __restrict__ o1b, int N) {
  const int lane = threadIdx.x & 63;
  const int node = blockIdx.x * (blockDim.x >> 6) + (threadIdx.x >> 6);
  if (node >= N) return;
  const unsigned int* hu = reinterpret_cast<const unsigned int*>(h);  // [N][64] pairs
  const int beg = row[node], end = row[node + 1];
  const float di = dinv[node];
  unsigned int hv = hu[(size_t)node * 64 + lane];
  float acc0 = bflo(hv) * di;   // h' = h*dinv[n]; self term = h'*di
  float acc1 = bfhi(hv) * di;
  int e = beg;
  for (; e + 8 <= end; e += 8) {
    uint2 m[8]; unsigned int hh[8];
#pragma unroll
    for (int i = 0; i < 8; ++i) m[i] = eadj[e + i];
#pragma unroll
    for (int i = 0; i < 8; ++i) hh[i] = hu[(size_t)m[i].x * 64 + lane];
#pragma unroll
    for (int i = 0; i < 8; ++i) {
      float nm = __builtin_bit_cast(float, m[i].y) * di;
      acc0 += bflo(hh[i]) * nm;
      acc1 += bfhi(hh[i]) * nm;
    }
  }
  for (; e < end; ++e) {
    uint2 m = eadj[e];
    float nm = __builtin_bit_cast(float, m.y) * di;
    unsigned int h0 = hu[(size_t)m.x * 64 + lane];
    acc0 += bflo(h0) * nm;
    acc1 += bfhi(h0) * nm;
  }
  float2 b = reinterpret_cast<const float2*>(bias)[lane];
  float r0 = fmaxf(acc0 + b.x, 0.f);
  float r1 = fmaxf(acc1 + b.y, 0.f);
  o1b[(size_t)node * 64 + lane] = packbf(r0, r1);
}

// ====== fused layer-2 aggregation + layer-3 GEMV; writes h3' = h3*dinv ======
__global__ void agg_l23_k(const int* __restrict__ row, const uint2* __restrict__ eadj,
                          const unsigned short* __restrict__ h2, const float* __restrict__ b2,
                          const float* __restrict__ W3, const float* __restrict__ dinv,
                          float* __restrict__ h3, int N) {
  const int lane = threadIdx.x & 63;
  const int half = lane >> 5;
  const int l = lane & 31;
  const int node = blockIdx.x * (blockDim.x >> 6) + (threadIdx.x >> 6);
  if (node >= N) return;
  const unsigned int* hu = reinterpret_cast<const unsigned int*>(h2);  // [N][32] pairs
  const int beg = row[node], end = row[node + 1];
  const float di = dinv[node];
  float acc0, acc1;
  {
    unsigned int hv = hu[(size_t)node * 32 + l];
    float dself = (half == 0) ? di : 0.f;
    acc0 = bflo(hv) * dself;
    acc1 = bfhi(hv) * dself;
  }
  int e = beg + half;
  for (; e + 6 < end; e += 8) {
    uint2 m[4]; unsigned int hh[4];
#pragma unroll
    for (int i = 0; i < 4; ++i) m[i] = eadj[e + 2 * i];
#pragma unroll
    for (int i = 0; i < 4; ++i) hh[i] = hu[(size_t)m[i].x * 32 + l];
#pragma unroll
    for (int i = 0; i < 4; ++i) {
      float nm = __builtin_bit_cast(float, m[i].y) * di;
      acc0 += bflo(hh[i]) * nm;
      acc1 += bfhi(hh[i]) * nm;
    }
  }
  for (; e < end; e += 2) {
    uint2 m = eadj[e];
    float nm = __builtin_bit_cast(float, m.y) * di;
    unsigned int hv = hu[(size_t)m.x * 32 + l];
    acc0 += bflo(hv) * nm;
    acc1 += bfhi(hv) * nm;
  }
  acc0 += __shfl_xor(acc0, 32, 64);
  acc1 += __shfl_xor(acc1, 32, 64);
  float2 bb = reinterpret_cast<const float2*>(b2)[l];
  float2 w3 = reinterpret_cast<const float2*>(W3)[l];
  float v = fmaxf(acc0 + bb.x, 0.f) * w3.x + fmaxf(acc1 + bb.y, 0.f) * w3.y;
#pragma unroll
  for (int off = 16; off > 0; off >>= 1) v += __shfl_xor(v, off, 64);
  if (lane == 0) h3[node] = v * di;   // pre-scale for layer-3 agg
}

// ====== layer-3 aggregation: thread per node (h3 pre-scaled) ======
__global__ void agg_csr1_k(const int* __restrict__ row, const uint2* __restrict__ eadj,
                           const float* __restrict__ h3, const float* __restrict__ b3,
                           const float* __restrict__ dinv, float* __restrict__ out, int N) {
  int n = blockIdx.x * blockDim.x + threadIdx.x;
  if (n >= N) return;
  float di = dinv[n];
  float acc = h3[n] * di;
  const int beg = row[n], end = row[n + 1];
  int e = beg;
  for (; e + 4 <= end; e += 4) {
    uint2 m[4]; float hv[4];
#pragma unroll
    for (int i = 0; i < 4; ++i) m[i] = eadj[e + i];
#pragma unroll
    for (int i = 0; i < 4; ++i) hv[i] = h3[m[i].x];
#pragma unroll
    for (int i = 0; i < 4; ++i)
      acc += hv[i] * (__builtin_bit_cast(float, m[i].y) * di);
  }
  for (; e < end; ++e) {
    uint2 m = eadj[e];
    acc += h3[m.x] * (__builtin_bit_cast(float, m.y) * di);
  }
  out[n] = acc + b3[0];
}

// ---------------- launch ----------------
extern "C" void kernel_launch(void* const* d_in, const int* in_sizes, int n_in,
                              void* d_out, int out_size, void* d_ws, size_t ws_size,
                              hipStream_t stream) {
  const float* x  = (const float*)d_in[0];
  const int*   ei = (const int*)d_in[1];
  const float* ea = (const float*)d_in[2];
  const float* W1 = (const float*)d_in[3];
  const float* b1 = (const float*)d_in[4];
  const float* W2 = (const float*)d_in[5];
  const float* b2 = (const float*)d_in[6];
  const float* W3 = (const float*)d_in[7];
  const float* b3 = (const float*)d_in[8];
  float* out = (float*)d_out;

  const int N = in_sizes[0] / 512;  // 100000
  const int E = in_sizes[2];        // 1600000
  const int* src = ei;
  const int* dst = ei + E;
  const int nbkt = (N + 127) >> 7;  // 782

  char* w = (char*)d_ws;
  auto alloc = [&](size_t bytes) {
    char* p = w; w += (bytes + 511) & ~(size_t)511; return p;
  };
  float* dinv         = (float*)alloc((size_t)N * 4);
  int*   rowp         = (int*)alloc((size_t)(N + 1) * 4);
  int*   gcount       = (int*)alloc(1024 * 4);
  int*   gbase        = (int*)alloc(1024 * 4);
  int*   gcursor      = (int*)alloc(1024 * 4);
  uint2* part         = (uint2*)alloc((size_t)E * 8);
  uint2* eadj         = (uint2*)alloc((size_t)E * 8);
  unsigned short* h1  = (unsigned short*)alloc((size_t)N * 128 * 2);
  unsigned int* o1b   = (unsigned int*)alloc((size_t)N * 64 * 4);   // relu(o1+b1) bf16x2
  unsigned short* h2  = (unsigned short*)alloc((size_t)N * 64 * 2);
  float* h3           = (float*)alloc((size_t)N * 4);
  unsigned short* wt1 = (unsigned short*)alloc(512 * 128 * 2);
  unsigned short* wt2 = (unsigned short*)alloc(128 * 64 * 2);

  const int TB = 256;
  const int pblocks = (E + CHUNK - 1) / CHUNK;   // 196

  hipMemsetAsync(gcount, 0, 1024 * 4, stream);

  // CSR build: bucket count -> scan -> partition -> per-bucket sort (+rowp,dinv)
  bkt_count_k<<<pblocks, TB, 0, stream>>>(dst, gcount, E, nbkt);
  bkt_scan_k<<<1, TB, 0, stream>>>(gcount, gbase, gcursor, nbkt);
  bkt_part_k<<<pblocks, TB, 0, stream>>>(src, dst, ea, gcursor, part, E, nbkt);
  bkt_build_k<<<nbkt, TB, 0, stream>>>(gbase, part, rowp, dinv, eadj, N, E, nbkt);
  conv_wt2_k<<<(512 * 128 + 128 * 64 + TB - 1) / TB, TB, 0, stream>>>(W1, wt1, W2, wt2);

  const int gblocks = (N + 127) / 128;
  const int ablocks = (N + 3) / 4;
  // layer 1
  gemm_f32a_k<128, 512><<<gblocks, TB, 0, stream>>>(x, wt1, dinv, h1, N);
  agg_csr128_k<<<ablocks, TB, 0, stream>>>(rowp, eadj, h1, b1, dinv, o1b, N);
  // layer 2 (A already relu'd bf16)
  gemm_bf16a_k<<<gblocks, TB, 0, stream>>>((const unsigned short*)o1b, wt2, dinv, h2, N);
  // fused layer-2 agg + layer-3 gemv
  agg_l23_k<<<ablocks, TB, 0, stream>>>(rowp, eadj, h2, b2, W3, dinv, h3, N);
  // layer 3 aggregation
  agg_csr1_k<<<(N + TB - 1) / TB, TB, 0, stream>>>(rowp, eadj, h3, b3, dinv, out, N);
}